// Round 15
// baseline (256.611 us; speedup 1.0000x reference)
//
#include <hip/hip_runtime.h>
#include <cstdint>
#include <cstddef>

// ---------------------------------------------------------------------------
// ExampleEncoderLayer on MI355X (gfx950)
// QKV now uses the 8-phase 256^2 schedule (counted vmcnt, never drained in
// the main loop); all other GEMMs keep the r5 structure (their grids can't
// fill the 256^2 template). k=3 conv on zero-row-padded Y1p. IN stats fused
// into conv3.
// ---------------------------------------------------------------------------

typedef __bf16 bf16_t;
typedef __attribute__((ext_vector_type(8))) __bf16 bf16x8;
typedef __attribute__((ext_vector_type(4))) __bf16 bf16x4;
typedef __attribute__((ext_vector_type(4))) float f32x4;
typedef __attribute__((ext_vector_type(8))) unsigned short u16x8;
typedef __attribute__((address_space(1))) unsigned int gu32;
typedef __attribute__((address_space(3))) unsigned int lu32;

#define EPSF 1e-5f

__device__ __forceinline__ void glds16(const void* g, void* l) {
  __builtin_amdgcn_global_load_lds((gu32*)g, (lu32*)l, 16, 0, 0);
}

__device__ __forceinline__ f32x4 mfma16(bf16x8 a, bf16x8 b, f32x4 c) {
  return __builtin_amdgcn_mfma_f32_16x16x32_bf16(a, b, c, 0, 0, 0);
}

// ---------------------------------------------------------------------------
// All 4 BN constant sets in one launch. grid 16: section = bid>>2.
// ---------------------------------------------------------------------------
struct BnAll {
  const float *g0, *b0, *m0, *v0;
  const float *g1, *b1, *m1, *v1, *cb1;
  const float *g2, *b2, *m2, *v2, *cb2;
  const float *g3, *b3, *m3, *v3, *cb3;
};
__global__ void bn_consts4_k(BnAll a, float* __restrict__ base) {
  const int sec = blockIdx.x >> 2;
  const int i = (blockIdx.x & 3) * 256 + threadIdx.x;
  const float *g, *b, *m, *v, *cb;
  switch (sec) {
    case 0: g = a.g0; b = a.b0; m = a.m0; v = a.v0; cb = nullptr; break;
    case 1: g = a.g1; b = a.b1; m = a.m1; v = a.v1; cb = a.cb1; break;
    case 2: g = a.g2; b = a.b2; m = a.m2; v = a.v2; cb = a.cb2; break;
    default: g = a.g3; b = a.b3; m = a.m3; v = a.v3; cb = a.cb3; break;
  }
  float s = g[i] * rsqrtf(v[i] + EPSF);
  base[sec * 2048 + i] = s;
  base[sec * 2048 + 1024 + i] = b[i] + ((cb ? cb[i] : 0.f) - m[i]) * s;
}

// ---------------------------------------------------------------------------
// BN(x) + transpose (N,C,L)->(N*L,C), bf16. grid (4,32,32), block 256.
// ---------------------------------------------------------------------------
__global__ __launch_bounds__(256)
void bn_transpose_k(const float* __restrict__ x, const float* __restrict__ sc,
                    const float* __restrict__ sh, bf16_t* __restrict__ H0b) {
  __shared__ float T[32][33];
  const int n = blockIdx.x, c0 = blockIdx.y * 32, l0 = blockIdx.z * 32;
  const int tx = threadIdx.x & 31, ty = threadIdx.x >> 5;
#pragma unroll
  for (int cc = 0; cc < 4; ++cc) {
    int c = c0 + ty + cc * 8;
    float v = x[((size_t)(n * 1024 + c) << 10) + l0 + tx];
    T[ty + cc * 8][tx] = v * sc[c] + sh[c];
  }
  __syncthreads();
#pragma unroll
  for (int cc = 0; cc < 4; ++cc) {
    int l = l0 + ty + cc * 8;
    float v = T[tx][ty + cc * 8];
    H0b[((size_t)(n * 1024 + l) << 10) + c0 + tx] = (bf16_t)v;
  }
}

// ---------------------------------------------------------------------------
// Weight prep, one launch: cast 6 square matrices + pack w2.
// ---------------------------------------------------------------------------
__global__ void prep_w_k(const float* __restrict__ s0, const float* __restrict__ s1,
                         const float* __restrict__ s2, const float* __restrict__ s3,
                         const float* __restrict__ s4, const float* __restrict__ s5,
                         const float* __restrict__ w2s,
                         bf16_t* __restrict__ d0, bf16_t* __restrict__ d1,
                         bf16_t* __restrict__ d2, bf16_t* __restrict__ d3,
                         bf16_t* __restrict__ d4, bf16_t* __restrict__ d5,
                         bf16_t* __restrict__ w2d) {
  const int b = blockIdx.x;
  if (b < 6144) {
    const int which = b >> 10;
    const int i = (b & 1023) * 256 + threadIdx.x;
    const float* s; bf16_t* d;
    switch (which) {
      case 0: s = s0; d = d0; break;
      case 1: s = s1; d = d1; break;
      case 2: s = s2; d = d2; break;
      case 3: s = s3; d = d3; break;
      case 4: s = s4; d = d4; break;
      default: s = s5; d = d5; break;
    }
    f32x4 v = *(const f32x4*)(s + (size_t)i * 4);
    bf16x4 o;
    o[0] = (bf16_t)v[0]; o[1] = (bf16_t)v[1]; o[2] = (bf16_t)v[2]; o[3] = (bf16_t)v[3];
    *(bf16x4*)(d + (size_t)i * 4) = o;
  } else {
    const int j0 = ((b - 6144) * 256 + (int)threadIdx.x) * 4;
    const int o = j0 / 3072;
    const int r = j0 - o * 3072;
    const int t = r >> 10;
    const int c0 = r & 1023;
    const float* src = w2s + (size_t)o * 3072 + t;
    bf16x4 ov;
#pragma unroll
    for (int e = 0; e < 4; ++e) ov[e] = (bf16_t)src[(c0 + e) * 3];
    *(bf16x4*)(w2d + (size_t)j0) = ov;
  }
}

// ---------------------------------------------------------------------------
// Zero Y1p's pad rows. Must run after attn (Y1p aliases Q). grid 32 x 256.
// ---------------------------------------------------------------------------
__global__ void zero_y1p_pads_k(bf16_t* __restrict__ Y1p) {
  int i = blockIdx.x * 256 + threadIdx.x;
  int n = i >> 11, r = (i >> 10) & 1, c = i & 1023;
  Y1p[(size_t)(n * 1026 + (r ? 1025 : 0)) * 1024 + c] = (bf16_t)0.f;
}

// ---------------------------------------------------------------------------
// QKV GEMM, 8-phase 256x256 schedule (m201 template, derived):
// M=4096, N=3072, K=1024. Grid 192 (=16x12, XCD-bijective), 512 threads =
// 8 waves (2M x 4N), per-wave output 128x64, acc[8][4]. LDS 128KB: A,B each
// 2dbuf x 2half x [128][64] bf16. Per K-tile, 4 phases, quadrant order
// (A0,B0)->(A0,B1)->(A1,B1)->(A1,B0): B-frags persist in regs (24 b128
// reads/K-tile, the minimum). One half-tile staged per phase; same-buffer
// stages (tile t+2 -> buffer t&1) placed after their region's last reader:
//   P1: T(t+1)A1 (free buf)   P2: T(t+1)B1 (free buf)
//   P3: T(t+2)B0 (B0 last read P2)   P4: T(t+2)A0 (A0 last read P3)
// s_waitcnt vmcnt(4) once per K-tile at P4 (2 half-tiles stay in flight
// ACROSS barriers; never drained). Raw s_barrier x2 per phase; setprio(1)
// around the MFMA cluster (T5). XOR-chunk swizzle identical to gemm_nt.
// Epilogue: Q*1/32 | K | V channel-major.
// ---------------------------------------------------------------------------
__global__ __launch_bounds__(512, 2)
void gemm_qkv8(const bf16_t* __restrict__ A, const bf16_t* __restrict__ B,
               bf16_t* __restrict__ out) {
  __shared__ __align__(16) bf16_t As[2][2][8192];
  __shared__ __align__(16) bf16_t Bs[2][2][8192];

  const int bid = blockIdx.x;
  const int wg = (bid & 7) * 24 + (bid >> 3);  // 192 = 8*24, bijective
  const int mt = wg / 12, nt = wg - mt * 12;
  const int tileM = mt * 256, tileN = nt * 256;

  const int tid = threadIdx.x;
  const int lane = tid & 63;
  const int w = tid >> 6;                 // 0..7
  const int wm = w >> 2, wn = w & 3;      // 2M x 4N
  const int l16 = lane & 15, gg = lane >> 4;
  const int bhalf = wn >> 1, bbase = (wn & 1) * 64;

  const bf16_t* Abase = A + ((size_t)tileM << 10);
  const bf16_t* Bbase = B + ((size_t)tileN << 10);

  // per-thread staging offsets (same r,s for every stage call)
  // STG(LDSHALF, GBASE, ROWBASE, KT): 2 glds16/thread = one 128x64 half-tile
#define STG(LDSHALF, GBASE, ROWBASE, KT)                                     \
  {                                                                          \
    _Pragma("unroll") for (int rd = 0; rd < 2; ++rd) {                       \
      int q = rd * 512 + tid; int rr = q >> 3; int ss = q & 7;               \
      glds16((GBASE) + (((size_t)((ROWBASE) + rr)) << 10) + ((KT) * 64) +    \
                 ((ss ^ (rr & 7)) * 8),                                      \
             &(LDSHALF)[q * 8]);                                             \
    }                                                                        \
  }

  bf16x8 aF[4][2], b0F[2][2], b1F[2][2];
  f32x4 acc[8][4];
#pragma unroll
  for (int m = 0; m < 8; ++m)
#pragma unroll
    for (int n = 0; n < 4; ++n) acc[m][n] = {0.f, 0.f, 0.f, 0.f};

#define READ_A(DB, AG)                                                       \
  _Pragma("unroll") for (int i = 0; i < 4; ++i)                              \
  _Pragma("unroll") for (int kk = 0; kk < 2; ++kk) {                         \
    int row = (AG) * 64 + i * 16 + l16;                                      \
    aF[i][kk] = *(const bf16x8*)&As[DB][wm][row * 64 +                       \
                                            (((kk * 4 + gg) ^ (l16 & 7)) * 8)]; \
  }
#define READ_B(DB, BG, DEST)                                                 \
  _Pragma("unroll") for (int jj = 0; jj < 2; ++jj)                           \
  _Pragma("unroll") for (int kk = 0; kk < 2; ++kk) {                         \
    int row = bbase + (BG) * 32 + jj * 16 + l16;                             \
    DEST[jj][kk] = *(const bf16x8*)&Bs[DB][bhalf][row * 64 +                 \
                                            (((kk * 4 + gg) ^ (l16 & 7)) * 8)]; \
  }
#define MMA_Q(AG, BG, BREG)                                                  \
  __builtin_amdgcn_s_setprio(1);                                             \
  _Pragma("unroll") for (int i = 0; i < 4; ++i)                              \
  _Pragma("unroll") for (int jj = 0; jj < 2; ++jj) {                         \
    acc[(AG)*4 + i][(BG)*2 + jj] =                                           \
        mfma16(aF[i][0], BREG[jj][0], acc[(AG)*4 + i][(BG)*2 + jj]);         \
    acc[(AG)*4 + i][(BG)*2 + jj] =                                           \
        mfma16(aF[i][1], BREG[jj][1], acc[(AG)*4 + i][(BG)*2 + jj]);         \
  }                                                                          \
  __builtin_amdgcn_s_setprio(0);

  // prologue: T0 all 4 halves + T1B0 + T1A0; wait T0 landed (4 loads in flight)
  STG(As[0][0], Abase, 0, 0);
  STG(As[0][1], Abase, 128, 0);
  STG(Bs[0][0], Bbase, 0, 0);
  STG(Bs[0][1], Bbase, 128, 0);
  STG(Bs[1][0], Bbase, 0, 1);
  STG(As[1][0], Abase, 0, 1);
  asm volatile("s_waitcnt vmcnt(4)" ::: "memory");
  __builtin_amdgcn_s_barrier();

  const int T = 16;
  for (int t = 0; t < T; ++t) {
    const int db = t & 1, dn = db ^ 1;
    // ---- P1: quadrant (A0,B0); stage T(t+1)A1 into free buffer
    READ_A(db, 0);
    READ_B(db, 0, b0F);
    if (t + 1 < T) STG(As[dn][1], Abase, 128, t + 1);
    __builtin_amdgcn_s_barrier();
    MMA_Q(0, 0, b0F);
    __builtin_amdgcn_s_barrier();
    // ---- P2: quadrant (A0,B1); stage T(t+1)B1 into free buffer
    READ_B(db, 1, b1F);
    if (t + 1 < T) STG(Bs[dn][1], Bbase, 128, t + 1);
    __builtin_amdgcn_s_barrier();
    MMA_Q(0, 1, b1F);
    __builtin_amdgcn_s_barrier();
    // ---- P3: quadrant (A1,B1); stage T(t+2)B0 (B0 region last read at P2)
    READ_A(db, 1);
    if (t + 2 < T) STG(Bs[db][0], Bbase, 0, t + 2);
    __builtin_amdgcn_s_barrier();
    MMA_Q(1, 1, b1F);
    __builtin_amdgcn_s_barrier();
    // ---- P4: quadrant (A1,B0); stage T(t+2)A0 (A0 region last read at P3);
    //      counted vmcnt: confirm T(t+1) landed, keep 2 half-tiles in flight
    if (t + 2 < T) STG(As[db][0], Abase, 0, t + 2);
    if (t < T - 2) {
      asm volatile("s_waitcnt vmcnt(4)" ::: "memory");
    } else if (t == T - 2) {
      asm volatile("s_waitcnt vmcnt(0)" ::: "memory");
    }
    __builtin_amdgcn_s_barrier();
    MMA_Q(1, 0, b0F);
    __builtin_amdgcn_s_barrier();
  }
#undef STG
#undef READ_A
#undef READ_B
#undef MMA_Q

#pragma unroll
  for (int m = 0; m < 8; ++m) {
#pragma unroll
    for (int n = 0; n < 4; ++n) {
#pragma unroll
      for (int j = 0; j < 4; ++j) {
        const int gr = tileM + wm * 128 + m * 16 + gg * 4 + j;
        const int gc = tileN + wn * 64 + n * 16 + l16;
        const int which = gc >> 10, c = gc & 1023;  // 256 | 1024: no straddle
        float v = acc[m][n][j] * (which == 0 ? 0.03125f : 1.f);
        if (which == 2)
          out[8388608 + ((size_t)(gr >> 10) << 20) + ((size_t)c << 10) + (gr & 1023)] =
              (bf16_t)v;
        else
          out[(size_t)which * 4194304 + ((size_t)gr << 10) + c] = (bf16_t)v;
      }
    }
  }
}

// ---------------------------------------------------------------------------
// NT GEMM (N=1024 shapes), r5 structure. lda/ldb separate; aPad/outPad map
// rows to the 1026-row zero-padded Y1p layout. statS/statQ: fused IN stats.
// ---------------------------------------------------------------------------
__global__ __launch_bounds__(256)
void gemm_nt(const bf16_t* __restrict__ A, const bf16_t* __restrict__ B, int K,
             int lda, int ldb, int aPad, int outPad, int nNT,
             const float* __restrict__ bnScale, const float* __restrict__ bnShift,
             int doRelu, const bf16_t* __restrict__ residB,
             bf16_t* __restrict__ outB, float* __restrict__ statS,
             float* __restrict__ statQ) {
  __shared__ __align__(16) bf16_t As[2][128 * 64];
  __shared__ __align__(16) bf16_t Bs[2][64 * 64];
  __shared__ float SrS[2][2][16], SrQ[2][2][16];

  const int bid = blockIdx.x;
  const int wg = (bid & 7) * (gridDim.x >> 3) + (bid >> 3);
  const int mt = wg / nNT, nt = wg - mt * nNT;
  const int tileM = mt * 128, tileN = nt * 64;

  const int tid = threadIdx.x;
  const int lane = tid & 63;
  const int w = tid >> 6, wr = w >> 1, wc = w & 1;
  const int l16 = lane & 15, g = lane >> 4;

  const bf16_t* aSrc[4];
  const bf16_t* bSrc[2];
#pragma unroll
  for (int it = 0; it < 4; ++it) {
    int q = it * 256 + tid, r = q >> 3, s = q & 7;
    int ar = tileM + r;
    if (aPad) ar = (ar >> 10) * 1026 + (ar & 1023);
    aSrc[it] = A + (size_t)ar * lda + ((s ^ (r & 7)) * 8);
  }
#pragma unroll
  for (int it = 0; it < 2; ++it) {
    int q = it * 256 + tid, r = q >> 3, s = q & 7;
    bSrc[it] = B + (size_t)(tileN + r) * ldb + ((s ^ (r & 7)) * 8);
  }

  f32x4 acc[4][2];
#pragma unroll
  for (int m = 0; m < 4; ++m)
#pragma unroll
    for (int n = 0; n < 2; ++n) acc[m][n] = {0.f, 0.f, 0.f, 0.f};

#pragma unroll
  for (int it = 0; it < 4; ++it) glds16(aSrc[it], &As[0][(it * 256 + tid) * 8]);
#pragma unroll
  for (int it = 0; it < 2; ++it) glds16(bSrc[it], &Bs[0][(it * 256 + tid) * 8]);
  __syncthreads();

  int buf = 0;
  for (int k0 = 0; k0 < K; k0 += 64) {
    if (k0 + 64 < K) {
#pragma unroll
      for (int it = 0; it < 4; ++it)
        glds16(aSrc[it] + k0 + 64, &As[buf ^ 1][(it * 256 + tid) * 8]);
#pragma unroll
      for (int it = 0; it < 2; ++it)
        glds16(bSrc[it] + k0 + 64, &Bs[buf ^ 1][(it * 256 + tid) * 8]);
    }
#pragma unroll
    for (int kk = 0; kk < 2; ++kk) {
      bf16x8 af[4], bfr[2];
#pragma unroll
      for (int m = 0; m < 4; ++m) {
        int r = wr * 64 + m * 16 + l16;
        af[m] = *(const bf16x8*)(&As[buf][r * 64 + (((kk * 4 + g) ^ (r & 7)) * 8)]);
      }
#pragma unroll
      for (int n = 0; n < 2; ++n) {
        int r = wc * 32 + n * 16 + l16;
        bfr[n] = *(const bf16x8*)(&Bs[buf][r * 64 + (((kk * 4 + g) ^ (r & 7)) * 8)]);
      }
#pragma unroll
      for (int m = 0; m < 4; ++m)
#pragma unroll
        for (int n = 0; n < 2; ++n) acc[m][n] = mfma16(af[m], bfr[n], acc[m][n]);
    }
    __syncthreads();
    buf ^= 1;
  }

  float sA[2] = {0.f, 0.f}, qA[2] = {0.f, 0.f};
#pragma unroll
  for (int m = 0; m < 4; ++m) {
#pragma unroll
    for (int n = 0; n < 2; ++n) {
#pragma unroll
      for (int j = 0; j < 4; ++j) {
        const int gr = tileM + wr * 64 + m * 16 + g * 4 + j;
        const int gc = tileN + wc * 32 + n * 16 + l16;
        float v = acc[m][n][j];
        if (bnScale) v = v * bnScale[gc] + bnShift[gc];
        if (residB) v += (float)residB[((size_t)gr << 10) + gc];
        if (doRelu) v = fmaxf(v, 0.f);
        size_t orow = gr;
        if (outPad) orow = (size_t)((gr >> 10) * 1026 + (gr & 1023) + 1);
        outB[orow * 1024 + gc] = (bf16_t)v;
        if (statS) { sA[n] += v; qA[n] += v * v; }
      }
    }
  }

  if (statS) {
#pragma unroll
    for (int n = 0; n < 2; ++n) {
      sA[n] += __shfl_xor(sA[n], 16); sA[n] += __shfl_xor(sA[n], 32);
      qA[n] += __shfl_xor(qA[n], 16); qA[n] += __shfl_xor(qA[n], 32);
    }
    if (wr == 1 && lane < 16) {
      SrS[wc][0][lane] = sA[0]; SrS[wc][1][lane] = sA[1];
      SrQ[wc][0][lane] = qA[0]; SrQ[wc][1][lane] = qA[1];
    }
    __syncthreads();
    if (wr == 0 && lane < 16) {
      const int z = mt & 7, nb = mt >> 3;
#pragma unroll
      for (int n = 0; n < 2; ++n) {
        const int gc = tileN + wc * 32 + n * 16 + lane;
        statS[z * 4096 + nb * 1024 + gc] = sA[n] + SrS[wc][n][lane];
        statQ[z * 4096 + nb * 1024 + gc] = qA[n] + SrQ[wc][n][lane];
      }
    }
  }
}

// ---------------------------------------------------------------------------
// Flash attention: GEMM-style LDS-staged K/V, double-buffered (unchanged).
// ---------------------------------------------------------------------------
__global__ __launch_bounds__(256)
void attn_fwd(const bf16_t* __restrict__ Qb, const bf16_t* __restrict__ Kb,
              const bf16_t* __restrict__ Vt, bf16_t* __restrict__ AO) {
  __shared__ __align__(16) bf16_t Ks[2][64][64];
  __shared__ __align__(16) bf16_t Vs[2][64][64];
  __shared__ __align__(16) bf16_t Ps[4][2][16][64];

  const int bid = blockIdx.x;
  const int xcd = bid & 7, idx = bid >> 3;
  const int head = xcd * 8 + (idx >> 3);
  const int qblk = idx & 7;
  const int n = head >> 4, h = head & 15;

  const int tid = threadIdx.x, lane = tid & 63, w = tid >> 6;
  const int l16 = lane & 15, g = lane >> 4;
  const int qbase = qblk * 128 + w * 32;

  bf16x8 aq[2][2];
#pragma unroll
  for (int s = 0; s < 2; ++s) {
    const size_t qoff = ((size_t)(n * 1024 + qbase + s * 16 + l16) << 10) + h * 64;
    aq[s][0] = *(const bf16x8*)(Qb + qoff + g * 8);
    aq[s][1] = *(const bf16x8*)(Qb + qoff + 32 + g * 8);
  }

  const bf16_t* Khead = Kb + ((size_t)(n * 1024) << 10) + h * 64;
  const bf16_t* Vhead = Vt + ((size_t)n << 20) + ((size_t)(h * 64) << 10);

  f32x4 oa[2][4];
  float psum[2][4];
#pragma unroll
  for (int s = 0; s < 2; ++s)
#pragma unroll
    for (int i = 0; i < 4; ++i) {
      oa[s][i] = {0.f, 0.f, 0.f, 0.f};
      psum[s][i] = 0.f;
    }

#pragma unroll
  for (int it = 0; it < 2; ++it) {
    int q = it * 256 + tid, r = q >> 3, c = q & 7;
    glds16(Khead + ((size_t)r << 10) + ((c ^ (r & 7)) * 8), &Ks[0][r][c * 8]);
    glds16(Vhead + ((size_t)r << 10) + ((c ^ (r & 7)) * 8), &Vs[0][r][c * 8]);
  }
  asm volatile("s_waitcnt vmcnt(0)" ::: "memory");
  __syncthreads();

  int buf = 0;
  for (int t = 0; t < 16; ++t) {
    if (t < 15) {
      const int kv0 = (t + 1) * 64;
#pragma unroll
      for (int it = 0; it < 2; ++it) {
        int q = it * 256 + tid, r = q >> 3, c = q & 7;
        glds16(Khead + ((size_t)(kv0 + r) << 10) + ((c ^ (r & 7)) * 8),
               &Ks[buf ^ 1][r][c * 8]);
        glds16(Vhead + ((size_t)r << 10) + kv0 + ((c ^ (r & 7)) * 8),
               &Vs[buf ^ 1][r][c * 8]);
      }
    }
    bf16x8 kf[8];
#pragma unroll
    for (int nf = 0; nf < 4; ++nf) {
      const int r = nf * 16 + l16;
      kf[2 * nf]     = *(const bf16x8*)(&Ks[buf][r][((g)     ^ (r & 7)) * 8]);
      kf[2 * nf + 1] = *(const bf16x8*)(&Ks[buf][r][((4 + g) ^ (r & 7)) * 8]);
    }
#pragma unroll
    for (int s = 0; s < 2; ++s) {
      f32x4 sc[4];
#pragma unroll
      for (int nf = 0; nf < 4; ++nf) sc[nf] = {0.f, 0.f, 0.f, 0.f};
#pragma unroll
      for (int nf = 0; nf < 4; ++nf) {
        sc[nf] = mfma16(aq[s][0], kf[2 * nf], sc[nf]);
        sc[nf] = mfma16(aq[s][1], kf[2 * nf + 1], sc[nf]);
      }
#pragma unroll
      for (int nf = 0; nf < 4; ++nf)
#pragma unroll
        for (int j = 0; j < 4; ++j) {
          float p = __expf(sc[nf][j]);
          psum[s][j] += p;
          const int row = g * 4 + j;
          const int ch = (nf * 2 + (l16 >> 3)) ^ (row & 7);
          Ps[w][s][row][ch * 8 + (l16 & 7)] = (bf16_t)p;
        }
    }
    bf16x8 vf[8];
#pragma unroll
    for (int nf = 0; nf < 4; ++nf) {
      const int r = nf * 16 + l16;
      vf[2 * nf]     = *(const bf16x8*)(&Vs[buf][r][((g)     ^ (r & 7)) * 8]);
      vf[2 * nf + 1] = *(const bf16x8*)(&Vs[buf][r][((4 + g) ^ (r & 7)) * 8]);
    }
#pragma unroll
    for (int s = 0; s < 2; ++s)
#pragma unroll
      for (int kk = 0; kk < 2; ++kk) {
        const int ch = (kk * 4 + g) ^ (l16 & 7);
        bf16x8 pa = *(const bf16x8*)(&Ps[w][s][l16][ch * 8]);
#pragma unroll
        for (int nf = 0; nf < 4; ++nf)
          oa[s][nf] = mfma16(pa, vf[2 * nf + kk], oa[s][nf]);
      }
    asm volatile("s_waitcnt vmcnt(0)" ::: "memory");
    __syncthreads();
    buf ^= 1;
  }

#pragma unroll
  for (int s = 0; s < 2; ++s)
#pragma unroll
    for (int j = 0; j < 4; ++j) {
      float sv = psum[s][j];
#pragma unroll
      for (int o = 1; o < 16; o <<= 1) sv += __shfl_xor(sv, o);
      psum[s][j] = sv;
    }
#pragma unroll
  for (int s = 0; s < 2; ++s)
#pragma unroll
    for (int nf = 0; nf < 4; ++nf)
#pragma unroll
      for (int j = 0; j < 4; ++j) {
        const int q = qbase + s * 16 + g * 4 + j;
        AO[((size_t)(n * 1024 + q) << 10) + h * 64 + nf * 16 + l16] =
            (bf16_t)(oa[s][nf][j] / psum[s][j]);
      }
}

// ---------------------------------------------------------------------------
// finalize: out[n,c,j] = relu((max(Z[n,2j,c],Z[n,2j+1,c]) - mean)*rstd)
// ---------------------------------------------------------------------------
__global__ __launch_bounds__(256)
void finalize_k(const bf16_t* __restrict__ Z, const float* __restrict__ ps,
                const float* __restrict__ pq, float* __restrict__ out) {
  __shared__ float T[32][33];
  const int n = blockIdx.x, c0 = blockIdx.y * 32, j0 = blockIdx.z * 32;
  const int tx = threadIdx.x & 31, ty = threadIdx.x >> 5;
  const int c = c0 + tx;
  float s = 0.f, q = 0.f;
#pragma unroll
  for (int z = 0; z < 8; ++z) {
    s += ps[z * 4096 + n * 1024 + c];
    q += pq[z * 4096 + n * 1024 + c];
  }
  const float mean = s * (1.f / 1024.f);
  const float var = q * (1.f / 1024.f) - mean * mean;
  const float rstd = rsqrtf(var + EPSF);
#pragma unroll
  for (int jj = 0; jj < 4; ++jj) {
    const int j = j0 + ty + jj * 8;
    float a = (float)Z[((size_t)(n * 1024 + 2 * j) << 10) + c];
    float b = (float)Z[((size_t)(n * 1024 + 2 * j + 1) << 10) + c];
    float v = (fmaxf(a, b) - mean) * rstd;
    T[ty + jj * 8][tx] = fmaxf(v, 0.f);
  }
  __syncthreads();
#pragma unroll
  for (int jj = 0; jj < 4; ++jj)
    out[((size_t)(n * 1024 + c0 + ty + jj * 8) << 9) + j0 + tx] = T[tx][ty + jj * 8];
}

// ---------------------------------------------------------------------------
extern "C" void kernel_launch(void* const* d_in, const int* in_sizes, int n_in,
                              void* d_out, int out_size, void* d_ws, size_t ws_size,
                              hipStream_t stream) {
  const float* x      = (const float*)d_in[0];
  const float* norm_g = (const float*)d_in[1];
  const float* norm_b = (const float*)d_in[2];
  const float* norm_m = (const float*)d_in[3];
  const float* norm_v = (const float*)d_in[4];
  const float* wq     = (const float*)d_in[5];
  const float* wk     = (const float*)d_in[6];
  const float* wv     = (const float*)d_in[7];
  const float* wo     = (const float*)d_in[8];
  const float* cw1    = (const float*)d_in[9];
  const float* cb1    = (const float*)d_in[10];
  const float* cw2    = (const float*)d_in[11];
  const float* cb2    = (const float*)d_in[12];
  const float* cw3    = (const float*)d_in[13];
  const float* cb3    = (const float*)d_in[14];
  const float* bn1_g  = (const float*)d_in[15];
  const float* bn1_b  = (const float*)d_in[16];
  const float* bn1_m  = (const float*)d_in[17];
  const float* bn1_v  = (const float*)d_in[18];
  const float* bn2_g  = (const float*)d_in[19];
  const float* bn2_b  = (const float*)d_in[20];
  const float* bn2_m  = (const float*)d_in[21];
  const float* bn2_v  = (const float*)d_in[22];
  const float* bn3_g  = (const float*)d_in[23];
  const float* bn3_b  = (const float*)d_in[24];
  const float* bn3_m  = (const float*)d_in[25];
  const float* bn3_v  = (const float*)d_in[26];

  char* ws = (char*)d_ws;
  const size_t MB = 1024 * 1024;
  bf16_t* Zb  = (bf16_t*)(ws);            // 8MB (conv3 out, bf16)
  bf16_t* H0b = (bf16_t*)(ws + 32 * MB);  // 8MB; dead after O-proj; reused as Y2
  bf16_t* Y2  = H0b;
  bf16_t* Qb  = (bf16_t*)(ws + 40 * MB);  // 8MB (Q) -- Q,K,V contiguous
  bf16_t* Kb  = (bf16_t*)(ws + 48 * MB);  // 8MB (K)
  bf16_t* Vt  = (bf16_t*)(ws + 56 * MB);  // 8MB (V)
  bf16_t* Y1p = Qb;                       // 8.4MB (4x1026 rows); post-attn reuse
  bf16_t* AOb = (bf16_t*)(ws + 64 * MB);  // 8MB (attn out)
  bf16_t* H2b = (bf16_t*)(ws + 72 * MB);  // 8MB (attn residual sum, bf16)
  bf16_t* wqb = (bf16_t*)(ws + 80 * MB);  // wq,wk,wv contiguous (3072,1024)
  bf16_t* wkb = (bf16_t*)(ws + 82 * MB);
  bf16_t* wvb = (bf16_t*)(ws + 84 * MB);
  bf16_t* wob = (bf16_t*)(ws + 86 * MB);
  bf16_t* w1b = (bf16_t*)(ws + 88 * MB);
  bf16_t* w3b = (bf16_t*)(ws + 90 * MB);
  bf16_t* w2b = (bf16_t*)(ws + 92 * MB);  // 6MB (O, tap*1024+c)
  float* cb   = (float*)(ws + 98 * MB);
  float* sc0 = cb,        * sh0 = cb + 1024;
  float* sc1 = cb + 2048, * sh1 = cb + 3072;
  float* sc2 = cb + 4096, * sh2 = cb + 5120;
  float* sc3 = cb + 6144, * sh3 = cb + 7168;
  float* ps  = cb + 8192;
  float* pq  = ps + 32768;

  BnAll ba = {norm_g, norm_b, norm_m, norm_v,
              bn1_g, bn1_b, bn1_m, bn1_v, cb1,
              bn2_g, bn2_b, bn2_m, bn2_v, cb2,
              bn3_g, bn3_b, bn3_m, bn3_v, cb3};
  bn_consts4_k<<<16, 256, 0, stream>>>(ba, cb);

  bn_transpose_k<<<dim3(4, 32, 32), 256, 0, stream>>>(x, sc0, sh0, H0b);

  prep_w_k<<<9216, 256, 0, stream>>>(wq, wk, wv, wo, cw1, cw3, cw2,
                                     wqb, wkb, wvb, wob, w1b, w3b, w2b);

  // Fused QKV projection: 8-phase 256x256 schedule, grid 192 x 512 threads.
  gemm_qkv8<<<192, 512, 0, stream>>>(H0b, wqb, Qb);

  attn_fwd<<<512, 256, 0, stream>>>(Qb, Kb, Vt, AOb);

  // Y1p pad rows (must be after attn: Y1p aliases Q)
  zero_y1p_pads_k<<<32, 256, 0, stream>>>(Y1p);

  // O-projection + attention residual (bf16 h) -> H2b
  gemm_nt<<<512, 256, 0, stream>>>(AOb, wob, 1024, 1024, 1024, 0, 0, 16,
                                   nullptr, nullptr, 0, H0b, H2b,
                                   nullptr, nullptr);
  // conv1 (k=1) + BN1 + ReLU -> Y1p (padded rows)
  gemm_nt<<<512, 256, 0, stream>>>(H2b, w1b, 1024, 1024, 1024, 0, 1, 16,
                                   sc1, sh1, 1, nullptr, Y1p,
                                   nullptr, nullptr);
  // conv2 (k=3) directly on Y1p: lda=1024 (one row per tap), ldb=3072, K=3072
  gemm_nt<<<512, 256, 0, stream>>>(Y1p, w2b, 3072, 1024, 3072, 1, 0, 16,
                                   sc2, sh2, 1, nullptr, Y2,
                                   nullptr, nullptr);
  // conv3 (k=1) + BN3 + residual(H2b) -> Zb (bf16) + fused IN stats
  gemm_nt<<<512, 256, 0, stream>>>(Y2, w3b, 1024, 1024, 1024, 0, 0, 16,
                                   sc3, sh3, 0, H2b, Zb, ps, pq);

  finalize_k<<<dim3(4, 32, 16), 256, 0, stream>>>(Zb, ps, pq, (float*)d_out);
}

// Round 16
// 246.976 us; speedup vs baseline: 1.0390x; 1.0390x over previous
//
#include <hip/hip_runtime.h>
#include <cstdint>
#include <cstddef>

// ---------------------------------------------------------------------------
// ExampleEncoderLayer on MI355X (gfx950)
// x:(4,1024,1024) f32 -> BN -> transpose -> +MHA -> conv1x1/BN/ReLU ->
// conv3/BN/ReLU -> conv1x1/BN -> +res -> InstanceNorm -> ReLU -> maxpool2
// bf16 NT-GEMMs via mfma_f32_16x16x32_bf16, r5 structure (128x64 tile,
// 2-deep LDS dbuf, 48KB -> 2-3 blocks/CU TLP hides the barrier drain).
// [r15 post-mortem: 8-phase QKV port was slower (64.8 vs 51 us) -- reverted.
//  Five sync-structure variants (r6/r7/r8/r13/r15) all lost to this one at
//  these grid sizes; structural plateau at ~500 TF/GEMM.]
// k=3 conv runs directly on zero-row-padded Y1p (row-stride 1024, K=3072).
// Instance-norm stats fused into conv3's epilogue.
// ---------------------------------------------------------------------------

typedef __bf16 bf16_t;
typedef __attribute__((ext_vector_type(8))) __bf16 bf16x8;
typedef __attribute__((ext_vector_type(4))) __bf16 bf16x4;
typedef __attribute__((ext_vector_type(4))) float f32x4;
typedef __attribute__((ext_vector_type(8))) unsigned short u16x8;
typedef __attribute__((address_space(1))) unsigned int gu32;
typedef __attribute__((address_space(3))) unsigned int lu32;

#define EPSF 1e-5f

__device__ __forceinline__ void glds16(const void* g, void* l) {
  __builtin_amdgcn_global_load_lds((gu32*)g, (lu32*)l, 16, 0, 0);
}

__device__ __forceinline__ f32x4 mfma16(bf16x8 a, bf16x8 b, f32x4 c) {
  return __builtin_amdgcn_mfma_f32_16x16x32_bf16(a, b, c, 0, 0, 0);
}

// ---------------------------------------------------------------------------
// All 4 BN constant sets in one launch. grid 16: section = bid>>2.
// ---------------------------------------------------------------------------
struct BnAll {
  const float *g0, *b0, *m0, *v0;
  const float *g1, *b1, *m1, *v1, *cb1;
  const float *g2, *b2, *m2, *v2, *cb2;
  const float *g3, *b3, *m3, *v3, *cb3;
};
__global__ void bn_consts4_k(BnAll a, float* __restrict__ base) {
  const int sec = blockIdx.x >> 2;
  const int i = (blockIdx.x & 3) * 256 + threadIdx.x;
  const float *g, *b, *m, *v, *cb;
  switch (sec) {
    case 0: g = a.g0; b = a.b0; m = a.m0; v = a.v0; cb = nullptr; break;
    case 1: g = a.g1; b = a.b1; m = a.m1; v = a.v1; cb = a.cb1; break;
    case 2: g = a.g2; b = a.b2; m = a.m2; v = a.v2; cb = a.cb2; break;
    default: g = a.g3; b = a.b3; m = a.m3; v = a.v3; cb = a.cb3; break;
  }
  float s = g[i] * rsqrtf(v[i] + EPSF);
  base[sec * 2048 + i] = s;
  base[sec * 2048 + 1024 + i] = b[i] + ((cb ? cb[i] : 0.f) - m[i]) * s;
}

// ---------------------------------------------------------------------------
// BN(x) + transpose (N,C,L)->(N*L,C), bf16. grid (4,32,32), block 256.
// ---------------------------------------------------------------------------
__global__ __launch_bounds__(256)
void bn_transpose_k(const float* __restrict__ x, const float* __restrict__ sc,
                    const float* __restrict__ sh, bf16_t* __restrict__ H0b) {
  __shared__ float T[32][33];
  const int n = blockIdx.x, c0 = blockIdx.y * 32, l0 = blockIdx.z * 32;
  const int tx = threadIdx.x & 31, ty = threadIdx.x >> 5;
#pragma unroll
  for (int cc = 0; cc < 4; ++cc) {
    int c = c0 + ty + cc * 8;
    float v = x[((size_t)(n * 1024 + c) << 10) + l0 + tx];
    T[ty + cc * 8][tx] = v * sc[c] + sh[c];
  }
  __syncthreads();
#pragma unroll
  for (int cc = 0; cc < 4; ++cc) {
    int l = l0 + ty + cc * 8;
    float v = T[tx][ty + cc * 8];
    H0b[((size_t)(n * 1024 + l) << 10) + c0 + tx] = (bf16_t)v;
  }
}

// ---------------------------------------------------------------------------
// Weight prep, one launch: blocks [0,6144) cast the 6 square matrices to
// bf16; blocks [6144,9216) pack w2 (O,C,3) -> (O, tap*1024+c) with
// OUTPUT-indexed addressing (coalesced bf16x4 stores, stride-3 reads).
// ---------------------------------------------------------------------------
__global__ void prep_w_k(const float* __restrict__ s0, const float* __restrict__ s1,
                         const float* __restrict__ s2, const float* __restrict__ s3,
                         const float* __restrict__ s4, const float* __restrict__ s5,
                         const float* __restrict__ w2s,
                         bf16_t* __restrict__ d0, bf16_t* __restrict__ d1,
                         bf16_t* __restrict__ d2, bf16_t* __restrict__ d3,
                         bf16_t* __restrict__ d4, bf16_t* __restrict__ d5,
                         bf16_t* __restrict__ w2d) {
  const int b = blockIdx.x;
  if (b < 6144) {
    const int which = b >> 10;
    const int i = (b & 1023) * 256 + threadIdx.x;
    const float* s; bf16_t* d;
    switch (which) {
      case 0: s = s0; d = d0; break;
      case 1: s = s1; d = d1; break;
      case 2: s = s2; d = d2; break;
      case 3: s = s3; d = d3; break;
      case 4: s = s4; d = d4; break;
      default: s = s5; d = d5; break;
    }
    f32x4 v = *(const f32x4*)(s + (size_t)i * 4);
    bf16x4 o;
    o[0] = (bf16_t)v[0]; o[1] = (bf16_t)v[1]; o[2] = (bf16_t)v[2]; o[3] = (bf16_t)v[3];
    *(bf16x4*)(d + (size_t)i * 4) = o;
  } else {
    const int j0 = ((b - 6144) * 256 + (int)threadIdx.x) * 4;
    const int o = j0 / 3072;
    const int r = j0 - o * 3072;
    const int t = r >> 10;
    const int c0 = r & 1023;
    const float* src = w2s + (size_t)o * 3072 + t;
    bf16x4 ov;
#pragma unroll
    for (int e = 0; e < 4; ++e) ov[e] = (bf16_t)src[(c0 + e) * 3];
    *(bf16x4*)(w2d + (size_t)j0) = ov;
  }
}

// ---------------------------------------------------------------------------
// Zero Y1p's pad rows (row 0 and 1025 of each 1026-row batch). 8192 elems.
// Must run after attn (Y1p aliases Q). grid 32 x 256.
// ---------------------------------------------------------------------------
__global__ void zero_y1p_pads_k(bf16_t* __restrict__ Y1p) {
  int i = blockIdx.x * 256 + threadIdx.x;
  int n = i >> 11, r = (i >> 10) & 1, c = i & 1023;
  Y1p[(size_t)(n * 1026 + (r ? 1025 : 0)) * 1024 + c] = (bf16_t)0.f;
}

// ---------------------------------------------------------------------------
// NT GEMM: out[gr,gc] = sum_k A[gr,k]*B[gc,k];  M=4096, N = nNT*64.
// r5 structure: tile 128x64, BK=64, 4 waves, wave-tile 64x32 (acc[4][2]),
// 2-deep LDS dbuf (48KB), global_load_lds(16B), XOR-chunk swizzle,
// XCD-bijective block swizzle. lda/ldb separate; aPad/outPad map rows to
// the 1026-row zero-padded Y1p layout (k=3 conv: one row per tap).
// Epilogues: qkv (Q*1/32 | K | V channel-major) or {BN, bf16 resid, relu};
// statS/statQ non-null -> fused instance-norm partials: per-wave shuffle
// reduce (xor16+xor32) + LDS cross-wr combine, one writer per (z,c) slot.
// ---------------------------------------------------------------------------
__global__ __launch_bounds__(256)
void gemm_nt(const bf16_t* __restrict__ A, const bf16_t* __restrict__ B, int K,
             int lda, int ldb, int aPad, int outPad, int nNT, int qkv,
             const float* __restrict__ bnScale, const float* __restrict__ bnShift,
             int doRelu, const bf16_t* __restrict__ residB,
             bf16_t* __restrict__ outB, float* __restrict__ statS,
             float* __restrict__ statQ) {
  __shared__ __align__(16) bf16_t As[2][128 * 64];
  __shared__ __align__(16) bf16_t Bs[2][64 * 64];
  __shared__ float SrS[2][2][16], SrQ[2][2][16];

  const int bid = blockIdx.x;
  const int wg = (bid & 7) * (gridDim.x >> 3) + (bid >> 3);  // XCD-bijective
  const int mt = wg / nNT, nt = wg - mt * nNT;
  const int tileM = mt * 128, tileN = nt * 64;

  const int tid = threadIdx.x;
  const int lane = tid & 63;
  const int w = tid >> 6, wr = w >> 1, wc = w & 1;
  const int l16 = lane & 15, g = lane >> 4;

  const bf16_t* aSrc[4];
  const bf16_t* bSrc[2];
#pragma unroll
  for (int it = 0; it < 4; ++it) {
    int q = it * 256 + tid, r = q >> 3, s = q & 7;
    int ar = tileM + r;
    if (aPad) ar = (ar >> 10) * 1026 + (ar & 1023);
    aSrc[it] = A + (size_t)ar * lda + ((s ^ (r & 7)) * 8);
  }
#pragma unroll
  for (int it = 0; it < 2; ++it) {
    int q = it * 256 + tid, r = q >> 3, s = q & 7;
    bSrc[it] = B + (size_t)(tileN + r) * ldb + ((s ^ (r & 7)) * 8);
  }

  f32x4 acc[4][2];
#pragma unroll
  for (int m = 0; m < 4; ++m)
#pragma unroll
    for (int n = 0; n < 2; ++n) acc[m][n] = {0.f, 0.f, 0.f, 0.f};

#pragma unroll
  for (int it = 0; it < 4; ++it) glds16(aSrc[it], &As[0][(it * 256 + tid) * 8]);
#pragma unroll
  for (int it = 0; it < 2; ++it) glds16(bSrc[it], &Bs[0][(it * 256 + tid) * 8]);
  __syncthreads();

  int buf = 0;
  for (int k0 = 0; k0 < K; k0 += 64) {
    if (k0 + 64 < K) {
#pragma unroll
      for (int it = 0; it < 4; ++it)
        glds16(aSrc[it] + k0 + 64, &As[buf ^ 1][(it * 256 + tid) * 8]);
#pragma unroll
      for (int it = 0; it < 2; ++it)
        glds16(bSrc[it] + k0 + 64, &Bs[buf ^ 1][(it * 256 + tid) * 8]);
    }
#pragma unroll
    for (int kk = 0; kk < 2; ++kk) {
      bf16x8 af[4], bfr[2];
#pragma unroll
      for (int m = 0; m < 4; ++m) {
        int r = wr * 64 + m * 16 + l16;
        af[m] = *(const bf16x8*)(&As[buf][r * 64 + (((kk * 4 + g) ^ (r & 7)) * 8)]);
      }
#pragma unroll
      for (int n = 0; n < 2; ++n) {
        int r = wc * 32 + n * 16 + l16;
        bfr[n] = *(const bf16x8*)(&Bs[buf][r * 64 + (((kk * 4 + g) ^ (r & 7)) * 8)]);
      }
#pragma unroll
      for (int m = 0; m < 4; ++m)
#pragma unroll
        for (int n = 0; n < 2; ++n) acc[m][n] = mfma16(af[m], bfr[n], acc[m][n]);
    }
    __syncthreads();
    buf ^= 1;
  }

  float sA[2] = {0.f, 0.f}, qA[2] = {0.f, 0.f};
#pragma unroll
  for (int m = 0; m < 4; ++m) {
#pragma unroll
    for (int n = 0; n < 2; ++n) {
#pragma unroll
      for (int j = 0; j < 4; ++j) {
        const int gr = tileM + wr * 64 + m * 16 + g * 4 + j;
        const int gc = tileN + wc * 32 + n * 16 + l16;
        if (qkv) {
          const int which = gc >> 10, c = gc & 1023;  // 64-tiles never straddle
          float v = acc[m][n][j] * (which == 0 ? 0.03125f : 1.f);
          if (which == 2)
            outB[8388608 + ((size_t)(gr >> 10) << 20) + ((size_t)c << 10) + (gr & 1023)] =
                (bf16_t)v;
          else
            outB[(size_t)which * 4194304 + ((size_t)gr << 10) + c] = (bf16_t)v;
        } else {
          float v = acc[m][n][j];
          if (bnScale) v = v * bnScale[gc] + bnShift[gc];
          if (residB) v += (float)residB[((size_t)gr << 10) + gc];
          if (doRelu) v = fmaxf(v, 0.f);
          size_t orow = gr;
          if (outPad) orow = (size_t)((gr >> 10) * 1026 + (gr & 1023) + 1);
          outB[orow * 1024 + gc] = (bf16_t)v;
          if (statS) { sA[n] += v; qA[n] += v * v; }
        }
      }
    }
  }

  if (statS) {
    // per-wave reduce over g (rows): lanes differing in bits 4,5 share a col
#pragma unroll
    for (int n = 0; n < 2; ++n) {
      sA[n] += __shfl_xor(sA[n], 16); sA[n] += __shfl_xor(sA[n], 32);
      qA[n] += __shfl_xor(qA[n], 16); qA[n] += __shfl_xor(qA[n], 32);
    }
    if (wr == 1 && lane < 16) {
      SrS[wc][0][lane] = sA[0]; SrS[wc][1][lane] = sA[1];
      SrQ[wc][0][lane] = qA[0]; SrQ[wc][1][lane] = qA[1];
    }
    __syncthreads();
    if (wr == 0 && lane < 16) {
      const int z = mt & 7, nb = mt >> 3;  // block rows = z-th 128-chunk of n
#pragma unroll
      for (int n = 0; n < 2; ++n) {
        const int gc = tileN + wc * 32 + n * 16 + lane;
        statS[z * 4096 + nb * 1024 + gc] = sA[n] + SrS[wc][n][lane];
        statQ[z * 4096 + nb * 1024 + gc] = qA[n] + SrQ[wc][n][lane];
      }
    }
  }
}

// ---------------------------------------------------------------------------
// Flash attention: GEMM-style LDS-staged K/V, double-buffered (unchanged).
// ---------------------------------------------------------------------------
__global__ __launch_bounds__(256)
void attn_fwd(const bf16_t* __restrict__ Qb, const bf16_t* __restrict__ Kb,
              const bf16_t* __restrict__ Vt, bf16_t* __restrict__ AO) {
  __shared__ __align__(16) bf16_t Ks[2][64][64];
  __shared__ __align__(16) bf16_t Vs[2][64][64];
  __shared__ __align__(16) bf16_t Ps[4][2][16][64];

  const int bid = blockIdx.x;
  const int xcd = bid & 7, idx = bid >> 3;
  const int head = xcd * 8 + (idx >> 3);
  const int qblk = idx & 7;
  const int n = head >> 4, h = head & 15;

  const int tid = threadIdx.x, lane = tid & 63, w = tid >> 6;
  const int l16 = lane & 15, g = lane >> 4;
  const int qbase = qblk * 128 + w * 32;

  bf16x8 aq[2][2];
#pragma unroll
  for (int s = 0; s < 2; ++s) {
    const size_t qoff = ((size_t)(n * 1024 + qbase + s * 16 + l16) << 10) + h * 64;
    aq[s][0] = *(const bf16x8*)(Qb + qoff + g * 8);
    aq[s][1] = *(const bf16x8*)(Qb + qoff + 32 + g * 8);
  }

  const bf16_t* Khead = Kb + ((size_t)(n * 1024) << 10) + h * 64;
  const bf16_t* Vhead = Vt + ((size_t)n << 20) + ((size_t)(h * 64) << 10);

  f32x4 oa[2][4];
  float psum[2][4];
#pragma unroll
  for (int s = 0; s < 2; ++s)
#pragma unroll
    for (int i = 0; i < 4; ++i) {
      oa[s][i] = {0.f, 0.f, 0.f, 0.f};
      psum[s][i] = 0.f;
    }

#pragma unroll
  for (int it = 0; it < 2; ++it) {
    int q = it * 256 + tid, r = q >> 3, c = q & 7;
    glds16(Khead + ((size_t)r << 10) + ((c ^ (r & 7)) * 8), &Ks[0][r][c * 8]);
    glds16(Vhead + ((size_t)r << 10) + ((c ^ (r & 7)) * 8), &Vs[0][r][c * 8]);
  }
  asm volatile("s_waitcnt vmcnt(0)" ::: "memory");
  __syncthreads();

  int buf = 0;
  for (int t = 0; t < 16; ++t) {
    if (t < 15) {
      const int kv0 = (t + 1) * 64;
#pragma unroll
      for (int it = 0; it < 2; ++it) {
        int q = it * 256 + tid, r = q >> 3, c = q & 7;
        glds16(Khead + ((size_t)(kv0 + r) << 10) + ((c ^ (r & 7)) * 8),
               &Ks[buf ^ 1][r][c * 8]);
        glds16(Vhead + ((size_t)r << 10) + kv0 + ((c ^ (r & 7)) * 8),
               &Vs[buf ^ 1][r][c * 8]);
      }
    }
    bf16x8 kf[8];
#pragma unroll
    for (int nf = 0; nf < 4; ++nf) {
      const int r = nf * 16 + l16;
      kf[2 * nf]     = *(const bf16x8*)(&Ks[buf][r][((g)     ^ (r & 7)) * 8]);
      kf[2 * nf + 1] = *(const bf16x8*)(&Ks[buf][r][((4 + g) ^ (r & 7)) * 8]);
    }
#pragma unroll
    for (int s = 0; s < 2; ++s) {
      f32x4 sc[4];
#pragma unroll
      for (int nf = 0; nf < 4; ++nf) sc[nf] = {0.f, 0.f, 0.f, 0.f};
#pragma unroll
      for (int nf = 0; nf < 4; ++nf) {
        sc[nf] = mfma16(aq[s][0], kf[2 * nf], sc[nf]);
        sc[nf] = mfma16(aq[s][1], kf[2 * nf + 1], sc[nf]);
      }
#pragma unroll
      for (int nf = 0; nf < 4; ++nf)
#pragma unroll
        for (int j = 0; j < 4; ++j) {
          float p = __expf(sc[nf][j]);
          psum[s][j] += p;
          const int row = g * 4 + j;
          const int ch = (nf * 2 + (l16 >> 3)) ^ (row & 7);
          Ps[w][s][row][ch * 8 + (l16 & 7)] = (bf16_t)p;
        }
    }
    bf16x8 vf[8];
#pragma unroll
    for (int nf = 0; nf < 4; ++nf) {
      const int r = nf * 16 + l16;
      vf[2 * nf]     = *(const bf16x8*)(&Vs[buf][r][((g)     ^ (r & 7)) * 8]);
      vf[2 * nf + 1] = *(const bf16x8*)(&Vs[buf][r][((4 + g) ^ (r & 7)) * 8]);
    }
#pragma unroll
    for (int s = 0; s < 2; ++s)
#pragma unroll
      for (int kk = 0; kk < 2; ++kk) {
        const int ch = (kk * 4 + g) ^ (l16 & 7);
        bf16x8 pa = *(const bf16x8*)(&Ps[w][s][l16][ch * 8]);
#pragma unroll
        for (int nf = 0; nf < 4; ++nf)
          oa[s][nf] = mfma16(pa, vf[2 * nf + kk], oa[s][nf]);
      }
    asm volatile("s_waitcnt vmcnt(0)" ::: "memory");
    __syncthreads();
    buf ^= 1;
  }

#pragma unroll
  for (int s = 0; s < 2; ++s)
#pragma unroll
    for (int j = 0; j < 4; ++j) {
      float sv = psum[s][j];
#pragma unroll
      for (int o = 1; o < 16; o <<= 1) sv += __shfl_xor(sv, o);
      psum[s][j] = sv;
    }
#pragma unroll
  for (int s = 0; s < 2; ++s)
#pragma unroll
    for (int nf = 0; nf < 4; ++nf)
#pragma unroll
      for (int j = 0; j < 4; ++j) {
        const int q = qbase + s * 16 + g * 4 + j;
        AO[((size_t)(n * 1024 + q) << 10) + h * 64 + nf * 16 + l16] =
            (bf16_t)(oa[s][nf][j] / psum[s][j]);
      }
}

// ---------------------------------------------------------------------------
// finalize: out[n,c,j] = relu((max(Z[n,2j,c],Z[n,2j+1,c]) - mean)*rstd)
// (maxpool commutes with monotone norm+relu). LDS transpose for coalescing.
// ---------------------------------------------------------------------------
__global__ __launch_bounds__(256)
void finalize_k(const bf16_t* __restrict__ Z, const float* __restrict__ ps,
                const float* __restrict__ pq, float* __restrict__ out) {
  __shared__ float T[32][33];
  const int n = blockIdx.x, c0 = blockIdx.y * 32, j0 = blockIdx.z * 32;
  const int tx = threadIdx.x & 31, ty = threadIdx.x >> 5;
  const int c = c0 + tx;
  float s = 0.f, q = 0.f;
#pragma unroll
  for (int z = 0; z < 8; ++z) {
    s += ps[z * 4096 + n * 1024 + c];
    q += pq[z * 4096 + n * 1024 + c];
  }
  const float mean = s * (1.f / 1024.f);
  const float var = q * (1.f / 1024.f) - mean * mean;
  const float rstd = rsqrtf(var + EPSF);
#pragma unroll
  for (int jj = 0; jj < 4; ++jj) {
    const int j = j0 + ty + jj * 8;
    float a = (float)Z[((size_t)(n * 1024 + 2 * j) << 10) + c];
    float b = (float)Z[((size_t)(n * 1024 + 2 * j + 1) << 10) + c];
    float v = (fmaxf(a, b) - mean) * rstd;
    T[ty + jj * 8][tx] = fmaxf(v, 0.f);
  }
  __syncthreads();
#pragma unroll
  for (int jj = 0; jj < 4; ++jj)
    out[((size_t)(n * 1024 + c0 + ty + jj * 8) << 9) + j0 + tx] = T[tx][ty + jj * 8];
}

// ---------------------------------------------------------------------------
extern "C" void kernel_launch(void* const* d_in, const int* in_sizes, int n_in,
                              void* d_out, int out_size, void* d_ws, size_t ws_size,
                              hipStream_t stream) {
  const float* x      = (const float*)d_in[0];
  const float* norm_g = (const float*)d_in[1];
  const float* norm_b = (const float*)d_in[2];
  const float* norm_m = (const float*)d_in[3];
  const float* norm_v = (const float*)d_in[4];
  const float* wq     = (const float*)d_in[5];
  const float* wk     = (const float*)d_in[6];
  const float* wv     = (const float*)d_in[7];
  const float* wo     = (const float*)d_in[8];
  const float* cw1    = (const float*)d_in[9];
  const float* cb1    = (const float*)d_in[10];
  const float* cw2    = (const float*)d_in[11];
  const float* cb2    = (const float*)d_in[12];
  const float* cw3    = (const float*)d_in[13];
  const float* cb3    = (const float*)d_in[14];
  const float* bn1_g  = (const float*)d_in[15];
  const float* bn1_b  = (const float*)d_in[16];
  const float* bn1_m  = (const float*)d_in[17];
  const float* bn1_v  = (const float*)d_in[18];
  const float* bn2_g  = (const float*)d_in[19];
  const float* bn2_b  = (const float*)d_in[20];
  const float* bn2_m  = (const float*)d_in[21];
  const float* bn2_v  = (const float*)d_in[22];
  const float* bn3_g  = (const float*)d_in[23];
  const float* bn3_b  = (const float*)d_in[24];
  const float* bn3_m  = (const float*)d_in[25];
  const float* bn3_v  = (const float*)d_in[26];

  char* ws = (char*)d_ws;
  const size_t MB = 1024 * 1024;
  bf16_t* Zb  = (bf16_t*)(ws);            // 8MB (conv3 out, bf16)
  bf16_t* H0b = (bf16_t*)(ws + 32 * MB);  // 8MB; dead after O-proj; reused as Y2
  bf16_t* Y2  = H0b;
  bf16_t* Qb  = (bf16_t*)(ws + 40 * MB);  // 8MB (Q) -- Q,K,V contiguous
  bf16_t* Kb  = (bf16_t*)(ws + 48 * MB);  // 8MB (K)
  bf16_t* Vt  = (bf16_t*)(ws + 56 * MB);  // 8MB (V)
  bf16_t* Y1p = Qb;                       // 8.4MB (4x1026 rows); post-attn reuse
  bf16_t* AOb = (bf16_t*)(ws + 64 * MB);  // 8MB (attn out)
  bf16_t* H2b = (bf16_t*)(ws + 72 * MB);  // 8MB (attn residual sum, bf16)
  bf16_t* wqb = (bf16_t*)(ws + 80 * MB);  // wq,wk,wv contiguous (3072,1024)
  bf16_t* wkb = (bf16_t*)(ws + 82 * MB);
  bf16_t* wvb = (bf16_t*)(ws + 84 * MB);
  bf16_t* wob = (bf16_t*)(ws + 86 * MB);
  bf16_t* w1b = (bf16_t*)(ws + 88 * MB);
  bf16_t* w3b = (bf16_t*)(ws + 90 * MB);
  bf16_t* w2b = (bf16_t*)(ws + 92 * MB);  // 6MB (O, tap*1024+c)
  float* cb   = (float*)(ws + 98 * MB);
  float* sc0 = cb,        * sh0 = cb + 1024;
  float* sc1 = cb + 2048, * sh1 = cb + 3072;
  float* sc2 = cb + 4096, * sh2 = cb + 5120;
  float* sc3 = cb + 6144, * sh3 = cb + 7168;
  float* ps  = cb + 8192;
  float* pq  = ps + 32768;

  BnAll ba = {norm_g, norm_b, norm_m, norm_v,
              bn1_g, bn1_b, bn1_m, bn1_v, cb1,
              bn2_g, bn2_b, bn2_m, bn2_v, cb2,
              bn3_g, bn3_b, bn3_m, bn3_v, cb3};
  bn_consts4_k<<<16, 256, 0, stream>>>(ba, cb);

  bn_transpose_k<<<dim3(4, 32, 32), 256, 0, stream>>>(x, sc0, sh0, H0b);

  prep_w_k<<<9216, 256, 0, stream>>>(wq, wk, wv, wo, cw1, cw3, cw2,
                                     wqb, wkb, wvb, wob, w1b, w3b, w2b);

  // Fused QKV projection: N=3072 (B = [wq;wk;wv]), grid 1536 (r10-proven).
  gemm_nt<<<1536, 256, 0, stream>>>(H0b, wqb, 1024, 1024, 1024, 0, 0, 48, 1,
                                    nullptr, nullptr, 0, nullptr, Qb,
                                    nullptr, nullptr);

  attn_fwd<<<512, 256, 0, stream>>>(Qb, Kb, Vt, AOb);

  // Y1p pad rows (must be after attn: Y1p aliases Q)
  zero_y1p_pads_k<<<32, 256, 0, stream>>>(Y1p);

  // O-projection + attention residual (bf16 h) -> H2b
  gemm_nt<<<512, 256, 0, stream>>>(AOb, wob, 1024, 1024, 1024, 0, 0, 16, 0,
                                   nullptr, nullptr, 0, H0b, H2b,
                                   nullptr, nullptr);
  // conv1 (k=1) + BN1 + ReLU -> Y1p (padded rows)
  gemm_nt<<<512, 256, 0, stream>>>(H2b, w1b, 1024, 1024, 1024, 0, 1, 16, 0,
                                   sc1, sh1, 1, nullptr, Y1p,
                                   nullptr, nullptr);
  // conv2 (k=3) directly on Y1p: lda=1024 (one row per tap), ldb=3072, K=3072
  gemm_nt<<<512, 256, 0, stream>>>(Y1p, w2b, 3072, 1024, 3072, 1, 0, 16, 0,
                                   sc2, sh2, 1, nullptr, Y2,
                                   nullptr, nullptr);
  // conv3 (k=1) + BN3 + residual(H2b) -> Zb (bf16) + fused IN stats
  gemm_nt<<<512, 256, 0, stream>>>(Y2, w3b, 1024, 1024, 1024, 0, 0, 16, 0,
                                   sc3, sh3, 0, H2b, Zb, ps, pq);

  finalize_k<<<dim3(4, 32, 16), 256, 0, stream>>>(Zb, ps, pq, (float*)d_out);
}

// Round 17
// 239.146 us; speedup vs baseline: 1.0730x; 1.0327x over previous
//
#include <hip/hip_runtime.h>
#include <cstdint>
#include <cstddef>

// ---------------------------------------------------------------------------
// ExampleEncoderLayer on MI355X (gfx950)
// x:(4,1024,1024) f32 -> BN -> transpose -> +MHA -> conv1x1/BN/ReLU ->
// conv3/BN/ReLU -> conv1x1/BN -> +res -> InstanceNorm -> ReLU -> maxpool2
// bf16 NT-GEMMs via mfma_f32_16x16x32_bf16, r5 structure (128x64 tile,
// 2-deep LDS dbuf, 48KB -> 2-3 blocks/CU TLP hides the barrier drain).
// [Structural plateau at ~500 TF/GEMM: 5 sync-structure variants
//  (r6/r7/r8/r13/r15) all lost to this structure at these grid sizes.]
// k=3 conv runs directly on zero-row-padded Y1p (row-stride 1024, K=3072);
// pad rows are zeroed by conv1's epilogue. IN stats fused into conv3.
// BN-consts fused into the weight-prep launch.
// ---------------------------------------------------------------------------

typedef __bf16 bf16_t;
typedef __attribute__((ext_vector_type(8))) __bf16 bf16x8;
typedef __attribute__((ext_vector_type(4))) __bf16 bf16x4;
typedef __attribute__((ext_vector_type(4))) float f32x4;
typedef __attribute__((ext_vector_type(8))) unsigned short u16x8;
typedef __attribute__((address_space(1))) unsigned int gu32;
typedef __attribute__((address_space(3))) unsigned int lu32;

#define EPSF 1e-5f

__device__ __forceinline__ void glds16(const void* g, void* l) {
  __builtin_amdgcn_global_load_lds((gu32*)g, (lu32*)l, 16, 0, 0);
}

__device__ __forceinline__ f32x4 mfma16(bf16x8 a, bf16x8 b, f32x4 c) {
  return __builtin_amdgcn_mfma_f32_16x16x32_bf16(a, b, c, 0, 0, 0);
}

struct BnAll {
  const float *g0, *b0, *m0, *v0;
  const float *g1, *b1, *m1, *v1, *cb1;
  const float *g2, *b2, *m2, *v2, *cb2;
  const float *g3, *b3, *m3, *v3, *cb3;
};

// ---------------------------------------------------------------------------
// Weight prep + BN consts, one launch (grid 9232):
//  blocks [0,6144):     cast the 6 square weight matrices to bf16
//  blocks [6144,9216):  pack w2 (O,C,3) -> (O, tap*1024+c), output-indexed
//  blocks [9216,9232):  the 4 BN constant sets (scale/shift per channel)
// ---------------------------------------------------------------------------
__global__ void prep_w_k(const float* __restrict__ s0, const float* __restrict__ s1,
                         const float* __restrict__ s2, const float* __restrict__ s3,
                         const float* __restrict__ s4, const float* __restrict__ s5,
                         const float* __restrict__ w2s,
                         bf16_t* __restrict__ d0, bf16_t* __restrict__ d1,
                         bf16_t* __restrict__ d2, bf16_t* __restrict__ d3,
                         bf16_t* __restrict__ d4, bf16_t* __restrict__ d5,
                         bf16_t* __restrict__ w2d, BnAll a,
                         float* __restrict__ cbase) {
  const int b = blockIdx.x;
  if (b < 6144) {
    const int which = b >> 10;
    const int i = (b & 1023) * 256 + threadIdx.x;
    const float* s; bf16_t* d;
    switch (which) {
      case 0: s = s0; d = d0; break;
      case 1: s = s1; d = d1; break;
      case 2: s = s2; d = d2; break;
      case 3: s = s3; d = d3; break;
      case 4: s = s4; d = d4; break;
      default: s = s5; d = d5; break;
    }
    f32x4 v = *(const f32x4*)(s + (size_t)i * 4);
    bf16x4 o;
    o[0] = (bf16_t)v[0]; o[1] = (bf16_t)v[1]; o[2] = (bf16_t)v[2]; o[3] = (bf16_t)v[3];
    *(bf16x4*)(d + (size_t)i * 4) = o;
  } else if (b < 9216) {
    const int j0 = ((b - 6144) * 256 + (int)threadIdx.x) * 4;
    const int o = j0 / 3072;
    const int r = j0 - o * 3072;
    const int t = r >> 10;
    const int c0 = r & 1023;
    const float* src = w2s + (size_t)o * 3072 + t;
    bf16x4 ov;
#pragma unroll
    for (int e = 0; e < 4; ++e) ov[e] = (bf16_t)src[(c0 + e) * 3];
    *(bf16x4*)(w2d + (size_t)j0) = ov;
  } else {
    const int bb = b - 9216;
    const int sec = bb >> 2;
    const int i = (bb & 3) * 256 + threadIdx.x;
    const float *g, *bt, *m, *v, *cb;
    switch (sec) {
      case 0: g = a.g0; bt = a.b0; m = a.m0; v = a.v0; cb = nullptr; break;
      case 1: g = a.g1; bt = a.b1; m = a.m1; v = a.v1; cb = a.cb1; break;
      case 2: g = a.g2; bt = a.b2; m = a.m2; v = a.v2; cb = a.cb2; break;
      default: g = a.g3; bt = a.b3; m = a.m3; v = a.v3; cb = a.cb3; break;
    }
    float s = g[i] * rsqrtf(v[i] + EPSF);
    cbase[sec * 2048 + i] = s;
    cbase[sec * 2048 + 1024 + i] = bt[i] + ((cb ? cb[i] : 0.f) - m[i]) * s;
  }
}

// ---------------------------------------------------------------------------
// BN(x) + transpose (N,C,L)->(N*L,C), bf16. grid (4,32,32), block 256.
// ---------------------------------------------------------------------------
__global__ __launch_bounds__(256)
void bn_transpose_k(const float* __restrict__ x, const float* __restrict__ sc,
                    const float* __restrict__ sh, bf16_t* __restrict__ H0b) {
  __shared__ float T[32][33];
  const int n = blockIdx.x, c0 = blockIdx.y * 32, l0 = blockIdx.z * 32;
  const int tx = threadIdx.x & 31, ty = threadIdx.x >> 5;
#pragma unroll
  for (int cc = 0; cc < 4; ++cc) {
    int c = c0 + ty + cc * 8;
    float v = x[((size_t)(n * 1024 + c) << 10) + l0 + tx];
    T[ty + cc * 8][tx] = v * sc[c] + sh[c];
  }
  __syncthreads();
#pragma unroll
  for (int cc = 0; cc < 4; ++cc) {
    int l = l0 + ty + cc * 8;
    float v = T[tx][ty + cc * 8];
    H0b[((size_t)(n * 1024 + l) << 10) + c0 + tx] = (bf16_t)v;
  }
}

// ---------------------------------------------------------------------------
// NT GEMM: out[gr,gc] = sum_k A[gr,k]*B[gc,k];  M=4096, N = nNT*64.
// r5 structure: tile 128x64, BK=64, 4 waves, wave-tile 64x32 (acc[4][2]),
// 2-deep LDS dbuf (48KB), global_load_lds(16B), XOR-chunk swizzle,
// XCD-bijective block swizzle. lda/ldb separate; aPad/outPad map rows to
// the 1026-row zero-padded Y1p layout (k=3 conv: one row per tap); outPad
// epilogue ALSO zeroes the adjacent pad row at batch edges (each pad elem
// written exactly once). Epilogues: qkv (Q*1/32 | K | V channel-major) or
// {BN, bf16 resid, relu}; statS/statQ -> fused IN partials (one writer/slot).
// ---------------------------------------------------------------------------
__global__ __launch_bounds__(256)
void gemm_nt(const bf16_t* __restrict__ A, const bf16_t* __restrict__ B, int K,
             int lda, int ldb, int aPad, int outPad, int nNT, int qkv,
             const float* __restrict__ bnScale, const float* __restrict__ bnShift,
             int doRelu, const bf16_t* __restrict__ residB,
             bf16_t* __restrict__ outB, float* __restrict__ statS,
             float* __restrict__ statQ) {
  __shared__ __align__(16) bf16_t As[2][128 * 64];
  __shared__ __align__(16) bf16_t Bs[2][64 * 64];
  __shared__ float SrS[2][2][16], SrQ[2][2][16];

  const int bid = blockIdx.x;
  const int wg = (bid & 7) * (gridDim.x >> 3) + (bid >> 3);  // XCD-bijective
  const int mt = wg / nNT, nt = wg - mt * nNT;
  const int tileM = mt * 128, tileN = nt * 64;

  const int tid = threadIdx.x;
  const int lane = tid & 63;
  const int w = tid >> 6, wr = w >> 1, wc = w & 1;
  const int l16 = lane & 15, g = lane >> 4;

  const bf16_t* aSrc[4];
  const bf16_t* bSrc[2];
#pragma unroll
  for (int it = 0; it < 4; ++it) {
    int q = it * 256 + tid, r = q >> 3, s = q & 7;
    int ar = tileM + r;
    if (aPad) ar = (ar >> 10) * 1026 + (ar & 1023);
    aSrc[it] = A + (size_t)ar * lda + ((s ^ (r & 7)) * 8);
  }
#pragma unroll
  for (int it = 0; it < 2; ++it) {
    int q = it * 256 + tid, r = q >> 3, s = q & 7;
    bSrc[it] = B + (size_t)(tileN + r) * ldb + ((s ^ (r & 7)) * 8);
  }

  f32x4 acc[4][2];
#pragma unroll
  for (int m = 0; m < 4; ++m)
#pragma unroll
    for (int n = 0; n < 2; ++n) acc[m][n] = {0.f, 0.f, 0.f, 0.f};

#pragma unroll
  for (int it = 0; it < 4; ++it) glds16(aSrc[it], &As[0][(it * 256 + tid) * 8]);
#pragma unroll
  for (int it = 0; it < 2; ++it) glds16(bSrc[it], &Bs[0][(it * 256 + tid) * 8]);
  __syncthreads();

  int buf = 0;
  for (int k0 = 0; k0 < K; k0 += 64) {
    if (k0 + 64 < K) {
#pragma unroll
      for (int it = 0; it < 4; ++it)
        glds16(aSrc[it] + k0 + 64, &As[buf ^ 1][(it * 256 + tid) * 8]);
#pragma unroll
      for (int it = 0; it < 2; ++it)
        glds16(bSrc[it] + k0 + 64, &Bs[buf ^ 1][(it * 256 + tid) * 8]);
    }
#pragma unroll
    for (int kk = 0; kk < 2; ++kk) {
      bf16x8 af[4], bfr[2];
#pragma unroll
      for (int m = 0; m < 4; ++m) {
        int r = wr * 64 + m * 16 + l16;
        af[m] = *(const bf16x8*)(&As[buf][r * 64 + (((kk * 4 + g) ^ (r & 7)) * 8)]);
      }
#pragma unroll
      for (int n = 0; n < 2; ++n) {
        int r = wc * 32 + n * 16 + l16;
        bfr[n] = *(const bf16x8*)(&Bs[buf][r * 64 + (((kk * 4 + g) ^ (r & 7)) * 8)]);
      }
#pragma unroll
      for (int m = 0; m < 4; ++m)
#pragma unroll
        for (int n = 0; n < 2; ++n) acc[m][n] = mfma16(af[m], bfr[n], acc[m][n]);
    }
    __syncthreads();
    buf ^= 1;
  }

  float sA[2] = {0.f, 0.f}, qA[2] = {0.f, 0.f};
#pragma unroll
  for (int m = 0; m < 4; ++m) {
#pragma unroll
    for (int n = 0; n < 2; ++n) {
#pragma unroll
      for (int j = 0; j < 4; ++j) {
        const int gr = tileM + wr * 64 + m * 16 + g * 4 + j;
        const int gc = tileN + wc * 32 + n * 16 + l16;
        if (qkv) {
          const int which = gc >> 10, c = gc & 1023;  // 64-tiles never straddle
          float v = acc[m][n][j] * (which == 0 ? 0.03125f : 1.f);
          if (which == 2)
            outB[8388608 + ((size_t)(gr >> 10) << 20) + ((size_t)c << 10) + (gr & 1023)] =
                (bf16_t)v;
          else
            outB[(size_t)which * 4194304 + ((size_t)gr << 10) + c] = (bf16_t)v;
        } else {
          float v = acc[m][n][j];
          if (bnScale) v = v * bnScale[gc] + bnShift[gc];
          if (residB) v += (float)residB[((size_t)gr << 10) + gc];
          if (doRelu) v = fmaxf(v, 0.f);
          size_t orow = gr;
          if (outPad) {
            const int l = gr & 1023;
            orow = (size_t)((gr >> 10) * 1026 + l + 1);
            // zero the adjacent pad row at batch edges (exactly once per col)
            if (l == 0) outB[(orow - 1) * 1024 + gc] = (bf16_t)0.f;
            if (l == 1023) outB[(orow + 1) * 1024 + gc] = (bf16_t)0.f;
          }
          outB[orow * 1024 + gc] = (bf16_t)v;
          if (statS) { sA[n] += v; qA[n] += v * v; }
        }
      }
    }
  }

  if (statS) {
#pragma unroll
    for (int n = 0; n < 2; ++n) {
      sA[n] += __shfl_xor(sA[n], 16); sA[n] += __shfl_xor(sA[n], 32);
      qA[n] += __shfl_xor(qA[n], 16); qA[n] += __shfl_xor(qA[n], 32);
    }
    if (wr == 1 && lane < 16) {
      SrS[wc][0][lane] = sA[0]; SrS[wc][1][lane] = sA[1];
      SrQ[wc][0][lane] = qA[0]; SrQ[wc][1][lane] = qA[1];
    }
    __syncthreads();
    if (wr == 0 && lane < 16) {
      const int z = mt & 7, nb = mt >> 3;
#pragma unroll
      for (int n = 0; n < 2; ++n) {
        const int gc = tileN + wc * 32 + n * 16 + lane;
        statS[z * 4096 + nb * 1024 + gc] = sA[n] + SrS[wc][n][lane];
        statQ[z * 4096 + nb * 1024 + gc] = qA[n] + SrQ[wc][n][lane];
      }
    }
  }
}

// ---------------------------------------------------------------------------
// Flash attention: GEMM-style LDS-staged K/V, double-buffered (unchanged).
// ---------------------------------------------------------------------------
__global__ __launch_bounds__(256)
void attn_fwd(const bf16_t* __restrict__ Qb, const bf16_t* __restrict__ Kb,
              const bf16_t* __restrict__ Vt, bf16_t* __restrict__ AO) {
  __shared__ __align__(16) bf16_t Ks[2][64][64];
  __shared__ __align__(16) bf16_t Vs[2][64][64];
  __shared__ __align__(16) bf16_t Ps[4][2][16][64];

  const int bid = blockIdx.x;
  const int xcd = bid & 7, idx = bid >> 3;
  const int head = xcd * 8 + (idx >> 3);
  const int qblk = idx & 7;
  const int n = head >> 4, h = head & 15;

  const int tid = threadIdx.x, lane = tid & 63, w = tid >> 6;
  const int l16 = lane & 15, g = lane >> 4;
  const int qbase = qblk * 128 + w * 32;

  bf16x8 aq[2][2];
#pragma unroll
  for (int s = 0; s < 2; ++s) {
    const size_t qoff = ((size_t)(n * 1024 + qbase + s * 16 + l16) << 10) + h * 64;
    aq[s][0] = *(const bf16x8*)(Qb + qoff + g * 8);
    aq[s][1] = *(const bf16x8*)(Qb + qoff + 32 + g * 8);
  }

  const bf16_t* Khead = Kb + ((size_t)(n * 1024) << 10) + h * 64;
  const bf16_t* Vhead = Vt + ((size_t)n << 20) + ((size_t)(h * 64) << 10);

  f32x4 oa[2][4];
  float psum[2][4];
#pragma unroll
  for (int s = 0; s < 2; ++s)
#pragma unroll
    for (int i = 0; i < 4; ++i) {
      oa[s][i] = {0.f, 0.f, 0.f, 0.f};
      psum[s][i] = 0.f;
    }

#pragma unroll
  for (int it = 0; it < 2; ++it) {
    int q = it * 256 + tid, r = q >> 3, c = q & 7;
    glds16(Khead + ((size_t)r << 10) + ((c ^ (r & 7)) * 8), &Ks[0][r][c * 8]);
    glds16(Vhead + ((size_t)r << 10) + ((c ^ (r & 7)) * 8), &Vs[0][r][c * 8]);
  }
  asm volatile("s_waitcnt vmcnt(0)" ::: "memory");
  __syncthreads();

  int buf = 0;
  for (int t = 0; t < 16; ++t) {
    if (t < 15) {
      const int kv0 = (t + 1) * 64;
#pragma unroll
      for (int it = 0; it < 2; ++it) {
        int q = it * 256 + tid, r = q >> 3, c = q & 7;
        glds16(Khead + ((size_t)(kv0 + r) << 10) + ((c ^ (r & 7)) * 8),
               &Ks[buf ^ 1][r][c * 8]);
        glds16(Vhead + ((size_t)r << 10) + kv0 + ((c ^ (r & 7)) * 8),
               &Vs[buf ^ 1][r][c * 8]);
      }
    }
    bf16x8 kf[8];
#pragma unroll
    for (int nf = 0; nf < 4; ++nf) {
      const int r = nf * 16 + l16;
      kf[2 * nf]     = *(const bf16x8*)(&Ks[buf][r][((g)     ^ (r & 7)) * 8]);
      kf[2 * nf + 1] = *(const bf16x8*)(&Ks[buf][r][((4 + g) ^ (r & 7)) * 8]);
    }
#pragma unroll
    for (int s = 0; s < 2; ++s) {
      f32x4 sc[4];
#pragma unroll
      for (int nf = 0; nf < 4; ++nf) sc[nf] = {0.f, 0.f, 0.f, 0.f};
#pragma unroll
      for (int nf = 0; nf < 4; ++nf) {
        sc[nf] = mfma16(aq[s][0], kf[2 * nf], sc[nf]);
        sc[nf] = mfma16(aq[s][1], kf[2 * nf + 1], sc[nf]);
      }
#pragma unroll
      for (int nf = 0; nf < 4; ++nf)
#pragma unroll
        for (int j = 0; j < 4; ++j) {
          float p = __expf(sc[nf][j]);
          psum[s][j] += p;
          const int row = g * 4 + j;
          const int ch = (nf * 2 + (l16 >> 3)) ^ (row & 7);
          Ps[w][s][row][ch * 8 + (l16 & 7)] = (bf16_t)p;
        }
    }
    bf16x8 vf[8];
#pragma unroll
    for (int nf = 0; nf < 4; ++nf) {
      const int r = nf * 16 + l16;
      vf[2 * nf]     = *(const bf16x8*)(&Vs[buf][r][((g)     ^ (r & 7)) * 8]);
      vf[2 * nf + 1] = *(const bf16x8*)(&Vs[buf][r][((4 + g) ^ (r & 7)) * 8]);
    }
#pragma unroll
    for (int s = 0; s < 2; ++s)
#pragma unroll
      for (int kk = 0; kk < 2; ++kk) {
        const int ch = (kk * 4 + g) ^ (l16 & 7);
        bf16x8 pa = *(const bf16x8*)(&Ps[w][s][l16][ch * 8]);
#pragma unroll
        for (int nf = 0; nf < 4; ++nf)
          oa[s][nf] = mfma16(pa, vf[2 * nf + kk], oa[s][nf]);
      }
    asm volatile("s_waitcnt vmcnt(0)" ::: "memory");
    __syncthreads();
    buf ^= 1;
  }

#pragma unroll
  for (int s = 0; s < 2; ++s)
#pragma unroll
    for (int j = 0; j < 4; ++j) {
      float sv = psum[s][j];
#pragma unroll
      for (int o = 1; o < 16; o <<= 1) sv += __shfl_xor(sv, o);
      psum[s][j] = sv;
    }
#pragma unroll
  for (int s = 0; s < 2; ++s)
#pragma unroll
    for (int nf = 0; nf < 4; ++nf)
#pragma unroll
      for (int j = 0; j < 4; ++j) {
        const int q = qbase + s * 16 + g * 4 + j;
        AO[((size_t)(n * 1024 + q) << 10) + h * 64 + nf * 16 + l16] =
            (bf16_t)(oa[s][nf][j] / psum[s][j]);
      }
}

// ---------------------------------------------------------------------------
// finalize: out[n,c,j] = relu((max(Z[n,2j,c],Z[n,2j+1,c]) - mean)*rstd)
// ---------------------------------------------------------------------------
__global__ __launch_bounds__(256)
void finalize_k(const bf16_t* __restrict__ Z, const float* __restrict__ ps,
                const float* __restrict__ pq, float* __restrict__ out) {
  __shared__ float T[32][33];
  const int n = blockIdx.x, c0 = blockIdx.y * 32, j0 = blockIdx.z * 32;
  const int tx = threadIdx.x & 31, ty = threadIdx.x >> 5;
  const int c = c0 + tx;
  float s = 0.f, q = 0.f;
#pragma unroll
  for (int z = 0; z < 8; ++z) {
    s += ps[z * 4096 + n * 1024 + c];
    q += pq[z * 4096 + n * 1024 + c];
  }
  const float mean = s * (1.f / 1024.f);
  const float var = q * (1.f / 1024.f) - mean * mean;
  const float rstd = rsqrtf(var + EPSF);
#pragma unroll
  for (int jj = 0; jj < 4; ++jj) {
    const int j = j0 + ty + jj * 8;
    float a = (float)Z[((size_t)(n * 1024 + 2 * j) << 10) + c];
    float b = (float)Z[((size_t)(n * 1024 + 2 * j + 1) << 10) + c];
    float v = (fmaxf(a, b) - mean) * rstd;
    T[ty + jj * 8][tx] = fmaxf(v, 0.f);
  }
  __syncthreads();
#pragma unroll
  for (int jj = 0; jj < 4; ++jj)
    out[((size_t)(n * 1024 + c0 + ty + jj * 8) << 9) + j0 + tx] = T[tx][ty + jj * 8];
}

// ---------------------------------------------------------------------------
extern "C" void kernel_launch(void* const* d_in, const int* in_sizes, int n_in,
                              void* d_out, int out_size, void* d_ws, size_t ws_size,
                              hipStream_t stream) {
  const float* x      = (const float*)d_in[0];
  const float* norm_g = (const float*)d_in[1];
  const float* norm_b = (const float*)d_in[2];
  const float* norm_m = (const float*)d_in[3];
  const float* norm_v = (const float*)d_in[4];
  const float* wq     = (const float*)d_in[5];
  const float* wk     = (const float*)d_in[6];
  const float* wv     = (const float*)d_in[7];
  const float* wo     = (const float*)d_in[8];
  const float* cw1    = (const float*)d_in[9];
  const float* cb1    = (const float*)d_in[10];
  const float* cw2    = (const float*)d_in[11];
  const float* cb2    = (const float*)d_in[12];
  const float* cw3    = (const float*)d_in[13];
  const float* cb3    = (const float*)d_in[14];
  const float* bn1_g  = (const float*)d_in[15];
  const float* bn1_b  = (const float*)d_in[16];
  const float* bn1_m  = (const float*)d_in[17];
  const float* bn1_v  = (const float*)d_in[18];
  const float* bn2_g  = (const float*)d_in[19];
  const float* bn2_b  = (const float*)d_in[20];
  const float* bn2_m  = (const float*)d_in[21];
  const float* bn2_v  = (const float*)d_in[22];
  const float* bn3_g  = (const float*)d_in[23];
  const float* bn3_b  = (const float*)d_in[24];
  const float* bn3_m  = (const float*)d_in[25];
  const float* bn3_v  = (const float*)d_in[26];

  char* ws = (char*)d_ws;
  const size_t MB = 1024 * 1024;
  bf16_t* Zb  = (bf16_t*)(ws);            // 8MB (conv3 out, bf16)
  bf16_t* H0b = (bf16_t*)(ws + 32 * MB);  // 8MB; dead after O-proj; reused as Y2
  bf16_t* Y2  = H0b;
  bf16_t* Qb  = (bf16_t*)(ws + 40 * MB);  // 8MB (Q) -- Q,K,V contiguous
  bf16_t* Kb  = (bf16_t*)(ws + 48 * MB);  // 8MB (K)
  bf16_t* Vt  = (bf16_t*)(ws + 56 * MB);  // 8MB (V)
  bf16_t* Y1p = Qb;                       // 8.4MB (4x1026 rows); post-attn reuse
  bf16_t* AOb = (bf16_t*)(ws + 64 * MB);  // 8MB (attn out)
  bf16_t* H2b = (bf16_t*)(ws + 72 * MB);  // 8MB (attn residual sum, bf16)
  bf16_t* wqb = (bf16_t*)(ws + 80 * MB);  // wq,wk,wv contiguous (3072,1024)
  bf16_t* wkb = (bf16_t*)(ws + 82 * MB);
  bf16_t* wvb = (bf16_t*)(ws + 84 * MB);
  bf16_t* wob = (bf16_t*)(ws + 86 * MB);
  bf16_t* w1b = (bf16_t*)(ws + 88 * MB);
  bf16_t* w3b = (bf16_t*)(ws + 90 * MB);
  bf16_t* w2b = (bf16_t*)(ws + 92 * MB);  // 6MB (O, tap*1024+c)
  float* cb   = (float*)(ws + 98 * MB);
  float* sc0 = cb,        * sh0 = cb + 1024;
  float* sc1 = cb + 2048, * sh1 = cb + 3072;
  float* sc2 = cb + 4096, * sh2 = cb + 5120;
  float* sc3 = cb + 6144, * sh3 = cb + 7168;
  float* ps  = cb + 8192;
  float* pq  = ps + 32768;

  BnAll ba = {norm_g, norm_b, norm_m, norm_v,
              bn1_g, bn1_b, bn1_m, bn1_v, cb1,
              bn2_g, bn2_b, bn2_m, bn2_v, cb2,
              bn3_g, bn3_b, bn3_m, bn3_v, cb3};

  // weight prep + BN consts (one launch; must precede bn_transpose)
  prep_w_k<<<9232, 256, 0, stream>>>(wq, wk, wv, wo, cw1, cw3, cw2,
                                     wqb, wkb, wvb, wob, w1b, w3b, w2b,
                                     ba, cb);

  bn_transpose_k<<<dim3(4, 32, 32), 256, 0, stream>>>(x, sc0, sh0, H0b);

  // Fused QKV projection: N=3072 (B = [wq;wk;wv]), grid 1536.
  gemm_nt<<<1536, 256, 0, stream>>>(H0b, wqb, 1024, 1024, 1024, 0, 0, 48, 1,
                                    nullptr, nullptr, 0, nullptr, Qb,
                                    nullptr, nullptr);

  attn_fwd<<<512, 256, 0, stream>>>(Qb, Kb, Vt, AOb);

  // O-projection + attention residual (bf16 h) -> H2b
  gemm_nt<<<512, 256, 0, stream>>>(AOb, wob, 1024, 1024, 1024, 0, 0, 16, 0,
                                   nullptr, nullptr, 0, H0b, H2b,
                                   nullptr, nullptr);
  // conv1 (k=1) + BN1 + ReLU -> Y1p (padded rows; epilogue zeroes pad rows)
  gemm_nt<<<512, 256, 0, stream>>>(H2b, w1b, 1024, 1024, 1024, 0, 1, 16, 0,
                                   sc1, sh1, 1, nullptr, Y1p,
                                   nullptr, nullptr);
  // conv2 (k=3) directly on Y1p: lda=1024 (one row per tap), ldb=3072, K=3072
  gemm_nt<<<512, 256, 0, stream>>>(Y1p, w2b, 3072, 1024, 3072, 1, 0, 16, 0,
                                   sc2, sh2, 1, nullptr, Y2,
                                   nullptr, nullptr);
  // conv3 (k=1) + BN3 + residual(H2b) -> Zb (bf16) + fused IN stats
  gemm_nt<<<512, 256, 0, stream>>>(Y2, w3b, 1024, 1024, 1024, 0, 0, 16, 0,
                                   sc3, sh3, 0, H2b, Zb, ps, pq);

  finalize_k<<<dim3(4, 32, 16), 256, 0, stream>>>(Zb, ps, pq, (float*)d_out);
}

// Round 18
// 237.323 us; speedup vs baseline: 1.0813x; 1.0077x over previous
//
#include <hip/hip_runtime.h>
#include <cstdint>
#include <cstddef>

// ---------------------------------------------------------------------------
// ExampleEncoderLayer on MI355X (gfx950)
// x:(4,1024,1024) f32 -> BN -> transpose -> +MHA -> conv1x1/BN/ReLU ->
// conv3/BN/ReLU -> conv1x1/BN -> +res -> InstanceNorm -> ReLU -> maxpool2
// bf16 NT-GEMMs via mfma_f32_16x16x32_bf16, r5 structure (128x64 tile,
// 2-deep LDS dbuf, 48KB -> 2-3 blocks/CU TLP hides the barrier drain).
// [Structural plateau at ~500 TF/GEMM: 5 sync-structure variants
//  (r6/r7/r8/r13/r15) all lost to this structure at these grid sizes.]
// k=3 conv runs directly on zero-row-padded Y1p (row-stride 1024, K=3072);
// pad rows zeroed by conv1's epilogue. IN stats fused into conv3.
// Weight-prep + BN-consts + BN-transpose all in ONE launch (transpose
// blocks compute their own 32 BN consts inline -> no cross-block dep).
// ---------------------------------------------------------------------------

typedef __bf16 bf16_t;
typedef __attribute__((ext_vector_type(8))) __bf16 bf16x8;
typedef __attribute__((ext_vector_type(4))) __bf16 bf16x4;
typedef __attribute__((ext_vector_type(4))) float f32x4;
typedef __attribute__((ext_vector_type(8))) unsigned short u16x8;
typedef __attribute__((address_space(1))) unsigned int gu32;
typedef __attribute__((address_space(3))) unsigned int lu32;

#define EPSF 1e-5f

__device__ __forceinline__ void glds16(const void* g, void* l) {
  __builtin_amdgcn_global_load_lds((gu32*)g, (lu32*)l, 16, 0, 0);
}

__device__ __forceinline__ f32x4 mfma16(bf16x8 a, bf16x8 b, f32x4 c) {
  return __builtin_amdgcn_mfma_f32_16x16x32_bf16(a, b, c, 0, 0, 0);
}

struct BnAll {
  const float *g0, *b0, *m0, *v0;
  const float *g1, *b1, *m1, *v1, *cb1;
  const float *g2, *b2, *m2, *v2, *cb2;
  const float *g3, *b3, *m3, *v3, *cb3;
};

// ---------------------------------------------------------------------------
// Fused prologue, one launch (grid 13328):
//  blocks [0,6144):      cast the 6 square weight matrices to bf16
//  blocks [6144,9216):   pack w2 (O,C,3) -> (O, tap*1024+c), output-indexed
//  blocks [9216,9232):   the 4 BN constant sets (scale/shift per channel)
//  blocks [9232,13328):  BN(x) + transpose (N,C,L)->(N*L,C) -> bf16 H0b;
//                        each block computes its own 32 BN consts inline
//                        (no dependency on the const blocks -> full overlap)
// ---------------------------------------------------------------------------
__global__ __launch_bounds__(256)
void prep_all_k(const float* __restrict__ s0, const float* __restrict__ s1,
                const float* __restrict__ s2, const float* __restrict__ s3,
                const float* __restrict__ s4, const float* __restrict__ s5,
                const float* __restrict__ w2s,
                bf16_t* __restrict__ d0, bf16_t* __restrict__ d1,
                bf16_t* __restrict__ d2, bf16_t* __restrict__ d3,
                bf16_t* __restrict__ d4, bf16_t* __restrict__ d5,
                bf16_t* __restrict__ w2d, BnAll a,
                float* __restrict__ cbase,
                const float* __restrict__ x, bf16_t* __restrict__ H0b) {
  const int b = blockIdx.x;
  if (b < 6144) {
    const int which = b >> 10;
    const int i = (b & 1023) * 256 + threadIdx.x;
    const float* s; bf16_t* d;
    switch (which) {
      case 0: s = s0; d = d0; break;
      case 1: s = s1; d = d1; break;
      case 2: s = s2; d = d2; break;
      case 3: s = s3; d = d3; break;
      case 4: s = s4; d = d4; break;
      default: s = s5; d = d5; break;
    }
    f32x4 v = *(const f32x4*)(s + (size_t)i * 4);
    bf16x4 o;
    o[0] = (bf16_t)v[0]; o[1] = (bf16_t)v[1]; o[2] = (bf16_t)v[2]; o[3] = (bf16_t)v[3];
    *(bf16x4*)(d + (size_t)i * 4) = o;
  } else if (b < 9216) {
    const int j0 = ((b - 6144) * 256 + (int)threadIdx.x) * 4;
    const int o = j0 / 3072;
    const int r = j0 - o * 3072;
    const int t = r >> 10;
    const int c0 = r & 1023;
    const float* src = w2s + (size_t)o * 3072 + t;
    bf16x4 ov;
#pragma unroll
    for (int e = 0; e < 4; ++e) ov[e] = (bf16_t)src[(c0 + e) * 3];
    *(bf16x4*)(w2d + (size_t)j0) = ov;
  } else if (b < 9232) {
    const int bb = b - 9216;
    const int sec = bb >> 2;
    const int i = (bb & 3) * 256 + threadIdx.x;
    const float *g, *bt, *m, *v, *cb;
    switch (sec) {
      case 0: g = a.g0; bt = a.b0; m = a.m0; v = a.v0; cb = nullptr; break;
      case 1: g = a.g1; bt = a.b1; m = a.m1; v = a.v1; cb = a.cb1; break;
      case 2: g = a.g2; bt = a.b2; m = a.m2; v = a.v2; cb = a.cb2; break;
      default: g = a.g3; bt = a.b3; m = a.m3; v = a.v3; cb = a.cb3; break;
    }
    float s = g[i] * rsqrtf(v[i] + EPSF);
    cbase[sec * 2048 + i] = s;
    cbase[sec * 2048 + 1024 + i] = bt[i] + ((cb ? cb[i] : 0.f) - m[i]) * s;
  } else {
    // BN(x) + transpose; consts computed in-block (32 rsqrtf, ~free)
    __shared__ float T[32][33];
    __shared__ float scL[32], shL[32];
    const int bb = b - 9232;               // [0,4096)
    const int n = bb >> 10;
    const int rem = bb & 1023;
    const int c0 = (rem >> 5) * 32, l0 = (rem & 31) * 32;
    const int tx = threadIdx.x & 31, ty = threadIdx.x >> 5;
    if (threadIdx.x < 32) {
      const int c = c0 + tx;
      float s = a.g0[c] * rsqrtf(a.v0[c] + EPSF);
      scL[tx] = s;
      shL[tx] = a.b0[c] - a.m0[c] * s;
    }
    __syncthreads();
#pragma unroll
    for (int cc = 0; cc < 4; ++cc) {
      int ci = ty + cc * 8;
      float v = x[((size_t)(n * 1024 + c0 + ci) << 10) + l0 + tx];
      T[ci][tx] = v * scL[ci] + shL[ci];
    }
    __syncthreads();
#pragma unroll
    for (int cc = 0; cc < 4; ++cc) {
      int l = l0 + ty + cc * 8;
      float v = T[tx][ty + cc * 8];
      H0b[((size_t)(n * 1024 + l) << 10) + c0 + tx] = (bf16_t)v;
    }
  }
}

// ---------------------------------------------------------------------------
// NT GEMM: out[gr,gc] = sum_k A[gr,k]*B[gc,k];  M=4096, N = nNT*64.
// r5 structure: tile 128x64, BK=64, 4 waves, wave-tile 64x32 (acc[4][2]),
// 2-deep LDS dbuf (48KB), global_load_lds(16B), XOR-chunk swizzle,
// XCD-bijective block swizzle. lda/ldb separate; aPad/outPad map rows to
// the 1026-row zero-padded Y1p layout (k=3 conv: one row per tap); outPad
// epilogue ALSO zeroes the adjacent pad row at batch edges (each pad elem
// written exactly once). Epilogues: qkv (Q*1/32 | K | V channel-major) or
// {BN, bf16 resid, relu}; statS/statQ -> fused IN partials (one writer/slot).
// ---------------------------------------------------------------------------
__global__ __launch_bounds__(256)
void gemm_nt(const bf16_t* __restrict__ A, const bf16_t* __restrict__ B, int K,
             int lda, int ldb, int aPad, int outPad, int nNT, int qkv,
             const float* __restrict__ bnScale, const float* __restrict__ bnShift,
             int doRelu, const bf16_t* __restrict__ residB,
             bf16_t* __restrict__ outB, float* __restrict__ statS,
             float* __restrict__ statQ) {
  __shared__ __align__(16) bf16_t As[2][128 * 64];
  __shared__ __align__(16) bf16_t Bs[2][64 * 64];
  __shared__ float SrS[2][2][16], SrQ[2][2][16];

  const int bid = blockIdx.x;
  const int wg = (bid & 7) * (gridDim.x >> 3) + (bid >> 3);  // XCD-bijective
  const int mt = wg / nNT, nt = wg - mt * nNT;
  const int tileM = mt * 128, tileN = nt * 64;

  const int tid = threadIdx.x;
  const int lane = tid & 63;
  const int w = tid >> 6, wr = w >> 1, wc = w & 1;
  const int l16 = lane & 15, g = lane >> 4;

  const bf16_t* aSrc[4];
  const bf16_t* bSrc[2];
#pragma unroll
  for (int it = 0; it < 4; ++it) {
    int q = it * 256 + tid, r = q >> 3, s = q & 7;
    int ar = tileM + r;
    if (aPad) ar = (ar >> 10) * 1026 + (ar & 1023);
    aSrc[it] = A + (size_t)ar * lda + ((s ^ (r & 7)) * 8);
  }
#pragma unroll
  for (int it = 0; it < 2; ++it) {
    int q = it * 256 + tid, r = q >> 3, s = q & 7;
    bSrc[it] = B + (size_t)(tileN + r) * ldb + ((s ^ (r & 7)) * 8);
  }

  f32x4 acc[4][2];
#pragma unroll
  for (int m = 0; m < 4; ++m)
#pragma unroll
    for (int n = 0; n < 2; ++n) acc[m][n] = {0.f, 0.f, 0.f, 0.f};

#pragma unroll
  for (int it = 0; it < 4; ++it) glds16(aSrc[it], &As[0][(it * 256 + tid) * 8]);
#pragma unroll
  for (int it = 0; it < 2; ++it) glds16(bSrc[it], &Bs[0][(it * 256 + tid) * 8]);
  __syncthreads();

  int buf = 0;
  for (int k0 = 0; k0 < K; k0 += 64) {
    if (k0 + 64 < K) {
#pragma unroll
      for (int it = 0; it < 4; ++it)
        glds16(aSrc[it] + k0 + 64, &As[buf ^ 1][(it * 256 + tid) * 8]);
#pragma unroll
      for (int it = 0; it < 2; ++it)
        glds16(bSrc[it] + k0 + 64, &Bs[buf ^ 1][(it * 256 + tid) * 8]);
    }
#pragma unroll
    for (int kk = 0; kk < 2; ++kk) {
      bf16x8 af[4], bfr[2];
#pragma unroll
      for (int m = 0; m < 4; ++m) {
        int r = wr * 64 + m * 16 + l16;
        af[m] = *(const bf16x8*)(&As[buf][r * 64 + (((kk * 4 + g) ^ (r & 7)) * 8)]);
      }
#pragma unroll
      for (int n = 0; n < 2; ++n) {
        int r = wc * 32 + n * 16 + l16;
        bfr[n] = *(const bf16x8*)(&Bs[buf][r * 64 + (((kk * 4 + g) ^ (r & 7)) * 8)]);
      }
#pragma unroll
      for (int m = 0; m < 4; ++m)
#pragma unroll
        for (int n = 0; n < 2; ++n) acc[m][n] = mfma16(af[m], bfr[n], acc[m][n]);
    }
    __syncthreads();
    buf ^= 1;
  }

  float sA[2] = {0.f, 0.f}, qA[2] = {0.f, 0.f};
#pragma unroll
  for (int m = 0; m < 4; ++m) {
#pragma unroll
    for (int n = 0; n < 2; ++n) {
#pragma unroll
      for (int j = 0; j < 4; ++j) {
        const int gr = tileM + wr * 64 + m * 16 + g * 4 + j;
        const int gc = tileN + wc * 32 + n * 16 + l16;
        if (qkv) {
          const int which = gc >> 10, c = gc & 1023;  // 64-tiles never straddle
          float v = acc[m][n][j] * (which == 0 ? 0.03125f : 1.f);
          if (which == 2)
            outB[8388608 + ((size_t)(gr >> 10) << 20) + ((size_t)c << 10) + (gr & 1023)] =
                (bf16_t)v;
          else
            outB[(size_t)which * 4194304 + ((size_t)gr << 10) + c] = (bf16_t)v;
        } else {
          float v = acc[m][n][j];
          if (bnScale) v = v * bnScale[gc] + bnShift[gc];
          if (residB) v += (float)residB[((size_t)gr << 10) + gc];
          if (doRelu) v = fmaxf(v, 0.f);
          size_t orow = gr;
          if (outPad) {
            const int l = gr & 1023;
            orow = (size_t)((gr >> 10) * 1026 + l + 1);
            if (l == 0) outB[(orow - 1) * 1024 + gc] = (bf16_t)0.f;
            if (l == 1023) outB[(orow + 1) * 1024 + gc] = (bf16_t)0.f;
          }
          outB[orow * 1024 + gc] = (bf16_t)v;
          if (statS) { sA[n] += v; qA[n] += v * v; }
        }
      }
    }
  }

  if (statS) {
#pragma unroll
    for (int n = 0; n < 2; ++n) {
      sA[n] += __shfl_xor(sA[n], 16); sA[n] += __shfl_xor(sA[n], 32);
      qA[n] += __shfl_xor(qA[n], 16); qA[n] += __shfl_xor(qA[n], 32);
    }
    if (wr == 1 && lane < 16) {
      SrS[wc][0][lane] = sA[0]; SrS[wc][1][lane] = sA[1];
      SrQ[wc][0][lane] = qA[0]; SrQ[wc][1][lane] = qA[1];
    }
    __syncthreads();
    if (wr == 0 && lane < 16) {
      const int z = mt & 7, nb = mt >> 3;
#pragma unroll
      for (int n = 0; n < 2; ++n) {
        const int gc = tileN + wc * 32 + n * 16 + lane;
        statS[z * 4096 + nb * 1024 + gc] = sA[n] + SrS[wc][n][lane];
        statQ[z * 4096 + nb * 1024 + gc] = qA[n] + SrQ[wc][n][lane];
      }
    }
  }
}

// ---------------------------------------------------------------------------
// Flash attention: GEMM-style LDS-staged K/V, double-buffered (unchanged).
// ---------------------------------------------------------------------------
__global__ __launch_bounds__(256)
void attn_fwd(const bf16_t* __restrict__ Qb, const bf16_t* __restrict__ Kb,
              const bf16_t* __restrict__ Vt, bf16_t* __restrict__ AO) {
  __shared__ __align__(16) bf16_t Ks[2][64][64];
  __shared__ __align__(16) bf16_t Vs[2][64][64];
  __shared__ __align__(16) bf16_t Ps[4][2][16][64];

  const int bid = blockIdx.x;
  const int xcd = bid & 7, idx = bid >> 3;
  const int head = xcd * 8 + (idx >> 3);
  const int qblk = idx & 7;
  const int n = head >> 4, h = head & 15;

  const int tid = threadIdx.x, lane = tid & 63, w = tid >> 6;
  const int l16 = lane & 15, g = lane >> 4;
  const int qbase = qblk * 128 + w * 32;

  bf16x8 aq[2][2];
#pragma unroll
  for (int s = 0; s < 2; ++s) {
    const size_t qoff = ((size_t)(n * 1024 + qbase + s * 16 + l16) << 10) + h * 64;
    aq[s][0] = *(const bf16x8*)(Qb + qoff + g * 8);
    aq[s][1] = *(const bf16x8*)(Qb + qoff + 32 + g * 8);
  }

  const bf16_t* Khead = Kb + ((size_t)(n * 1024) << 10) + h * 64;
  const bf16_t* Vhead = Vt + ((size_t)n << 20) + ((size_t)(h * 64) << 10);

  f32x4 oa[2][4];
  float psum[2][4];
#pragma unroll
  for (int s = 0; s < 2; ++s)
#pragma unroll
    for (int i = 0; i < 4; ++i) {
      oa[s][i] = {0.f, 0.f, 0.f, 0.f};
      psum[s][i] = 0.f;
    }

#pragma unroll
  for (int it = 0; it < 2; ++it) {
    int q = it * 256 + tid, r = q >> 3, c = q & 7;
    glds16(Khead + ((size_t)r << 10) + ((c ^ (r & 7)) * 8), &Ks[0][r][c * 8]);
    glds16(Vhead + ((size_t)r << 10) + ((c ^ (r & 7)) * 8), &Vs[0][r][c * 8]);
  }
  asm volatile("s_waitcnt vmcnt(0)" ::: "memory");
  __syncthreads();

  int buf = 0;
  for (int t = 0; t < 16; ++t) {
    if (t < 15) {
      const int kv0 = (t + 1) * 64;
#pragma unroll
      for (int it = 0; it < 2; ++it) {
        int q = it * 256 + tid, r = q >> 3, c = q & 7;
        glds16(Khead + ((size_t)(kv0 + r) << 10) + ((c ^ (r & 7)) * 8),
               &Ks[buf ^ 1][r][c * 8]);
        glds16(Vhead + ((size_t)r << 10) + kv0 + ((c ^ (r & 7)) * 8),
               &Vs[buf ^ 1][r][c * 8]);
      }
    }
    bf16x8 kf[8];
#pragma unroll
    for (int nf = 0; nf < 4; ++nf) {
      const int r = nf * 16 + l16;
      kf[2 * nf]     = *(const bf16x8*)(&Ks[buf][r][((g)     ^ (r & 7)) * 8]);
      kf[2 * nf + 1] = *(const bf16x8*)(&Ks[buf][r][((4 + g) ^ (r & 7)) * 8]);
    }
#pragma unroll
    for (int s = 0; s < 2; ++s) {
      f32x4 sc[4];
#pragma unroll
      for (int nf = 0; nf < 4; ++nf) sc[nf] = {0.f, 0.f, 0.f, 0.f};
#pragma unroll
      for (int nf = 0; nf < 4; ++nf) {
        sc[nf] = mfma16(aq[s][0], kf[2 * nf], sc[nf]);
        sc[nf] = mfma16(aq[s][1], kf[2 * nf + 1], sc[nf]);
      }
#pragma unroll
      for (int nf = 0; nf < 4; ++nf)
#pragma unroll
        for (int j = 0; j < 4; ++j) {
          float p = __expf(sc[nf][j]);
          psum[s][j] += p;
          const int row = g * 4 + j;
          const int ch = (nf * 2 + (l16 >> 3)) ^ (row & 7);
          Ps[w][s][row][ch * 8 + (l16 & 7)] = (bf16_t)p;
        }
    }
    bf16x8 vf[8];
#pragma unroll
    for (int nf = 0; nf < 4; ++nf) {
      const int r = nf * 16 + l16;
      vf[2 * nf]     = *(const bf16x8*)(&Vs[buf][r][((g)     ^ (r & 7)) * 8]);
      vf[2 * nf + 1] = *(const bf16x8*)(&Vs[buf][r][((4 + g) ^ (r & 7)) * 8]);
    }
#pragma unroll
    for (int s = 0; s < 2; ++s)
#pragma unroll
      for (int kk = 0; kk < 2; ++kk) {
        const int ch = (kk * 4 + g) ^ (l16 & 7);
        bf16x8 pa = *(const bf16x8*)(&Ps[w][s][l16][ch * 8]);
#pragma unroll
        for (int nf = 0; nf < 4; ++nf)
          oa[s][nf] = mfma16(pa, vf[2 * nf + kk], oa[s][nf]);
      }
    asm volatile("s_waitcnt vmcnt(0)" ::: "memory");
    __syncthreads();
    buf ^= 1;
  }

#pragma unroll
  for (int s = 0; s < 2; ++s)
#pragma unroll
    for (int j = 0; j < 4; ++j) {
      float sv = psum[s][j];
#pragma unroll
      for (int o = 1; o < 16; o <<= 1) sv += __shfl_xor(sv, o);
      psum[s][j] = sv;
    }
#pragma unroll
  for (int s = 0; s < 2; ++s)
#pragma unroll
    for (int nf = 0; nf < 4; ++nf)
#pragma unroll
      for (int j = 0; j < 4; ++j) {
        const int q = qbase + s * 16 + g * 4 + j;
        AO[((size_t)(n * 1024 + q) << 10) + h * 64 + nf * 16 + l16] =
            (bf16_t)(oa[s][nf][j] / psum[s][j]);
      }
}

// ---------------------------------------------------------------------------
// finalize: out[n,c,j] = relu((max(Z[n,2j,c],Z[n,2j+1,c]) - mean)*rstd)
// ---------------------------------------------------------------------------
__global__ __launch_bounds__(256)
void finalize_k(const bf16_t* __restrict__ Z, const float* __restrict__ ps,
                const float* __restrict__ pq, float* __restrict__ out) {
  __shared__ float T[32][33];
  const int n = blockIdx.x, c0 = blockIdx.y * 32, j0 = blockIdx.z * 32;
  const int tx = threadIdx.x & 31, ty = threadIdx.x >> 5;
  const int c = c0 + tx;
  float s = 0.f, q = 0.f;
#pragma unroll
  for (int z = 0; z < 8; ++z) {
    s += ps[z * 4096 + n * 1024 + c];
    q += pq[z * 4096 + n * 1024 + c];
  }
  const float mean = s * (1.f / 1024.f);
  const float var = q * (1.f / 1024.f) - mean * mean;
  const float rstd = rsqrtf(var + EPSF);
#pragma unroll
  for (int jj = 0; jj < 4; ++jj) {
    const int j = j0 + ty + jj * 8;
    float a = (float)Z[((size_t)(n * 1024 + 2 * j) << 10) + c];
    float b = (float)Z[((size_t)(n * 1024 + 2 * j + 1) << 10) + c];
    float v = (fmaxf(a, b) - mean) * rstd;
    T[ty + jj * 8][tx] = fmaxf(v, 0.f);
  }
  __syncthreads();
#pragma unroll
  for (int jj = 0; jj < 4; ++jj)
    out[((size_t)(n * 1024 + c0 + ty + jj * 8) << 9) + j0 + tx] = T[tx][ty + jj * 8];
}

// ---------------------------------------------------------------------------
extern "C" void kernel_launch(void* const* d_in, const int* in_sizes, int n_in,
                              void* d_out, int out_size, void* d_ws, size_t ws_size,
                              hipStream_t stream) {
  const float* x      = (const float*)d_in[0];
  const float* norm_g = (const float*)d_in[1];
  const float* norm_b = (const float*)d_in[2];
  const float* norm_m = (const float*)d_in[3];
  const float* norm_v = (const float*)d_in[4];
  const float* wq     = (const float*)d_in[5];
  const float* wk     = (const float*)d_in[6];
  const float* wv     = (const float*)d_in[7];
  const float* wo     = (const float*)d_in[8];
  const float* cw1    = (const float*)d_in[9];
  const float* cb1    = (const float*)d_in[10];
  const float* cw2    = (const float*)d_in[11];
  const float* cb2    = (const float*)d_in[12];
  const float* cw3    = (const float*)d_in[13];
  const float* cb3    = (const float*)d_in[14];
  const float* bn1_g  = (const float*)d_in[15];
  const float* bn1_b  = (const float*)d_in[16];
  const float* bn1_m  = (const float*)d_in[17];
  const float* bn1_v  = (const float*)d_in[18];
  const float* bn2_g  = (const float*)d_in[19];
  const float* bn2_b  = (const float*)d_in[20];
  const float* bn2_m  = (const float*)d_in[21];
  const float* bn2_v  = (const float*)d_in[22];
  const float* bn3_g  = (const float*)d_in[23];
  const float* bn3_b  = (const float*)d_in[24];
  const float* bn3_m  = (const float*)d_in[25];
  const float* bn3_v  = (const float*)d_in[26];

  char* ws = (char*)d_ws;
  const size_t MB = 1024 * 1024;
  bf16_t* Zb  = (bf16_t*)(ws);            // 8MB (conv3 out, bf16)
  bf16_t* H0b = (bf16_t*)(ws + 32 * MB);  // 8MB; dead after O-proj; reused as Y2
  bf16_t* Y2  = H0b;
  bf16_t* Qb  = (bf16_t*)(ws + 40 * MB);  // 8MB (Q) -- Q,K,V contiguous
  bf16_t* Kb  = (bf16_t*)(ws + 48 * MB);  // 8MB (K)
  bf16_t* Vt  = (bf16_t*)(ws + 56 * MB);  // 8MB (V)
  bf16_t* Y1p = Qb;                       // 8.4MB (4x1026 rows); post-attn reuse
  bf16_t* AOb = (bf16_t*)(ws + 64 * MB);  // 8MB (attn out)
  bf16_t* H2b = (bf16_t*)(ws + 72 * MB);  // 8MB (attn residual sum, bf16)
  bf16_t* wqb = (bf16_t*)(ws + 80 * MB);  // wq,wk,wv contiguous (3072,1024)
  bf16_t* wkb = (bf16_t*)(ws + 82 * MB);
  bf16_t* wvb = (bf16_t*)(ws + 84 * MB);
  bf16_t* wob = (bf16_t*)(ws + 86 * MB);
  bf16_t* w1b = (bf16_t*)(ws + 88 * MB);
  bf16_t* w3b = (bf16_t*)(ws + 90 * MB);
  bf16_t* w2b = (bf16_t*)(ws + 92 * MB);  // 6MB (O, tap*1024+c)
  float* cb   = (float*)(ws + 98 * MB);
  float* sc1 = cb + 2048, * sh1 = cb + 3072;
  float* sc2 = cb + 4096, * sh2 = cb + 5120;
  float* sc3 = cb + 6144, * sh3 = cb + 7168;
  float* ps  = cb + 8192;
  float* pq  = ps + 32768;

  BnAll ba = {norm_g, norm_b, norm_m, norm_v,
              bn1_g, bn1_b, bn1_m, bn1_v, cb1,
              bn2_g, bn2_b, bn2_m, bn2_v, cb2,
              bn3_g, bn3_b, bn3_m, bn3_v, cb3};

  // fused prologue: weight prep + BN consts + BN-transpose (one launch)
  prep_all_k<<<13328, 256, 0, stream>>>(wq, wk, wv, wo, cw1, cw3, cw2,
                                        wqb, wkb, wvb, wob, w1b, w3b, w2b,
                                        ba, cb, x, H0b);

  // Fused QKV projection: N=3072 (B = [wq;wk;wv]), grid 1536.
  gemm_nt<<<1536, 256, 0, stream>>>(H0b, wqb, 1024, 1024, 1024, 0, 0, 48, 1,
                                    nullptr, nullptr, 0, nullptr, Qb,
                                    nullptr, nullptr);

  attn_fwd<<<512, 256, 0, stream>>>(Qb, Kb, Vt, AOb);

  // O-projection + attention residual (bf16 h) -> H2b
  gemm_nt<<<512, 256, 0, stream>>>(AOb, wob, 1024, 1024, 1024, 0, 0, 16, 0,
                                   nullptr, nullptr, 0, H0b, H2b,
                                   nullptr, nullptr);
  // conv1 (k=1) + BN1 + ReLU -> Y1p (padded rows; epilogue zeroes pad rows)
  gemm_nt<<<512, 256, 0, stream>>>(H2b, w1b, 1024, 1024, 1024, 0, 1, 16, 0,
                                   sc1, sh1, 1, nullptr, Y1p,
                                   nullptr, nullptr);
  // conv2 (k=3) directly on Y1p: lda=1024 (one row per tap), ldb=3072, K=3072
  gemm_nt<<<512, 256, 0, stream>>>(Y1p, w2b, 3072, 1024, 3072, 1, 0, 16, 0,
                                   sc2, sh2, 1, nullptr, Y2,
                                   nullptr, nullptr);
  // conv3 (k=1) + BN3 + residual(H2b) -> Zb (bf16) + fused IN stats
  gemm_nt<<<512, 256, 0, stream>>>(Y2, w3b, 1024, 1024, 1024, 0, 0, 16, 0,
                                   sc3, sh3, 0, H2b, Zb, ps, pq);

  finalize_k<<<dim3(4, 32, 16), 256, 0, stream>>>(Zb, ps, pq, (float*)d_out);
}